// Round 1
// baseline (1712.392 us; speedup 1.0000x reference)
//
#include <hip/hip_runtime.h>
#include <hip/hip_bf16.h>

#define N_NODES 50000
#define N_EDGES 640000
#define D 128
#define T 128
#define KE 416      // edge-MLP K padded: [h_src 0-127 | h_dst 128-255 | t_emb 256-383 | dist 384 | 0-pad ..415]
#define KN 384      // node-MLP K: [h | m_i | t_emb_nodes]
#define MT 64       // rows (edges/nodes) per block

typedef __attribute__((ext_vector_type(8))) short  bf16x8;
typedef __attribute__((ext_vector_type(4))) float  f32x4;
typedef __attribute__((ext_vector_type(4))) unsigned short u16x4;
typedef __attribute__((ext_vector_type(8))) unsigned short u16x8;

__device__ __forceinline__ float silu_f(float x) { return x / (1.0f + __expf(-x)); }

__device__ __forceinline__ unsigned short f2bf(float x) {
    union { float f; unsigned u; } v; v.f = x;
    unsigned r = v.u + 0x7fffu + ((v.u >> 16) & 1u);   // RNE
    return (unsigned short)(r >> 16);
}

// ---------------------------------------------------------------- prep: transpose weights -> bf16 [col][k]
__global__ __launch_bounds__(256) void prep_weights(
    const float* __restrict__ We1, const float* __restrict__ We2,
    const float* __restrict__ Wc1, const float* __restrict__ Wn1,
    const float* __restrict__ Wn2,
    unsigned short* __restrict__ Wt1, unsigned short* __restrict__ Wt2,
    unsigned short* __restrict__ Wtc1, unsigned short* __restrict__ Wtn1,
    unsigned short* __restrict__ Wtn2)
{
    const int c = blockIdx.x;     // output channel 0..127
    const int t = threadIdx.x;
    for (int k = t; k < KE; k += 256) {
        float v = 0.0f;
        if (k < 256)      v = We1[(size_t)k * D + c];          // h_src | h_dst
        else if (k < 384) v = We1[(size_t)(k + 1) * D + c];    // t_emb (orig rows 257..384)
        else if (k == 384) v = We1[(size_t)256 * D + c];       // dist_sq (orig row 256)
        Wt1[(size_t)c * KE + k] = f2bf(v);
    }
    for (int k = t; k < D; k += 256) {
        Wt2 [(size_t)c * D + k] = f2bf(We2[(size_t)k * D + c]);
        Wtc1[(size_t)c * D + k] = f2bf(Wc1[(size_t)k * D + c]);
        Wtn2[(size_t)c * D + k] = f2bf(Wn2[(size_t)k * D + c]);
    }
    for (int k = t; k < KN; k += 256) {
        Wtn1[(size_t)c * KN + k] = f2bf(Wn1[(size_t)k * D + c]);
    }
}

// ---------------------------------------------------------------- fused edge kernel
// per block: 64 edges. A-tile (edge_input, bf16, XOR-swizzled) in LDS.
// GEMM operands swapped: mfma(A=W^T frag, B=edge frag) -> lane holds 4 consecutive
// output channels of one edge => SiLU'd outputs pack to contiguous 8B LDS writes.
__global__ __launch_bounds__(256) void edge_kernel(
    const float* __restrict__ h, const float* __restrict__ diff_cart,
    const float* __restrict__ dist_sq, const int* __restrict__ esrc,
    const int* __restrict__ edst, const float* __restrict__ temb,
    const unsigned short* __restrict__ Wt1, const float* __restrict__ be1,
    const unsigned short* __restrict__ Wt2, const float* __restrict__ be2,
    const unsigned short* __restrict__ Wtc1, const float* __restrict__ bc1,
    const float* __restrict__ wc2,
    float* __restrict__ m_i, float* __restrict__ coord_out)
{
    __shared__ __align__(16) unsigned short smem[MT * KE];  // 53248 B; X overlays [0,16K), m_ij at [16K,32K)
    __shared__ float cwp[4 * MT];
    __shared__ int s_src[MT], s_dst[MT];

    char* sbytes = (char*)smem;
    const int tid = threadIdx.x, blk = blockIdx.x;
    const int w = tid >> 6, l = tid & 63, lo = l & 15, hi = l >> 4;
    const int cb = w * 32;

    if (tid < MT) { s_src[tid] = esrc[blk * MT + tid]; s_dst[tid] = edst[blk * MT + tid]; }

    // ---- build A tile: 4 threads/row, 13 chunks of 8 cols each
    {
        const int r = tid >> 2, q = tid & 3;
        const int ge = blk * MT + r;
        const int src = esrc[ge], dst = edst[ge];
        const float* hs = h + (size_t)src * D;
        const float* hd = h + (size_t)dst * D;
        const float* tp = temb + (size_t)ge * T;
        const float dsq = dist_sq[ge];
        #pragma unroll
        for (int i = 0; i < 13; ++i) {
            const int ch = q * 13 + i, col = ch * 8;
            float vals[8];
            if (col < 384) {
                const float* p = (col < 128) ? (hs + col) : (col < 256) ? (hd + col - 128) : (tp + col - 256);
                f32x4 v0 = *(const f32x4*)p;
                f32x4 v1 = *(const f32x4*)(p + 4);
                #pragma unroll
                for (int j = 0; j < 4; ++j) { vals[j] = v0[j]; vals[4 + j] = v1[j]; }
            } else {
                #pragma unroll
                for (int j = 0; j < 8; ++j) vals[j] = 0.0f;
                if (col == 384) vals[0] = dsq;
            }
            u16x8 u;
            #pragma unroll
            for (int j = 0; j < 8; ++j) u[j] = f2bf(vals[j]);
            int b = (r * (KE * 2) + col * 2) ^ ((r & 7) << 4);
            *(u16x8*)(sbytes + b) = u;
        }
    }
    __syncthreads();

    // ---- GEMM1: K = 416 (13 chunks of 32)
    f32x4 acc[2][4];
    #pragma unroll
    for (int ci = 0; ci < 2; ++ci)
        #pragma unroll
        for (int ej = 0; ej < 4; ++ej) acc[ci][ej] = (f32x4){0.f, 0.f, 0.f, 0.f};
    {
        const unsigned short* w0 = Wt1 + (size_t)(cb + lo) * KE + hi * 8;
        const unsigned short* w1 = Wt1 + (size_t)(cb + 16 + lo) * KE + hi * 8;
        #pragma unroll
        for (int kk = 0; kk < 13; ++kk) {
            bf16x8 a0 = *(const bf16x8*)(w0 + kk * 32);
            bf16x8 a1 = *(const bf16x8*)(w1 + kk * 32);
            bf16x8 bfr[4];
            #pragma unroll
            for (int ej = 0; ej < 4; ++ej) {
                int b = ((16 * ej + lo) * (KE * 2) + kk * 64 + hi * 16) ^ ((lo & 7) << 4);
                bfr[ej] = *(const bf16x8*)(sbytes + b);
            }
            #pragma unroll
            for (int ej = 0; ej < 4; ++ej) {
                acc[0][ej] = __builtin_amdgcn_mfma_f32_16x16x32_bf16(a0, bfr[ej], acc[0][ej], 0, 0, 0);
                acc[1][ej] = __builtin_amdgcn_mfma_f32_16x16x32_bf16(a1, bfr[ej], acc[1][ej], 0, 0, 0);
            }
        }
    }
    float bv[2][4];
    #pragma unroll
    for (int ci = 0; ci < 2; ++ci)
        #pragma unroll
        for (int r = 0; r < 4; ++r) bv[ci][r] = be1[cb + 16 * ci + hi * 4 + r];
    __syncthreads();   // all A-tile reads done before X overlays it

    // ---- bias+SiLU, pack X (bf16) into LDS [0,16K)
    #pragma unroll
    for (int ci = 0; ci < 2; ++ci)
        #pragma unroll
        for (int ej = 0; ej < 4; ++ej) {
            u16x4 u;
            #pragma unroll
            for (int r = 0; r < 4; ++r) u[r] = f2bf(silu_f(acc[ci][ej][r] + bv[ci][r]));
            const int e = 16 * ej + lo, c0 = cb + 16 * ci + hi * 4;
            int b = (e * 256 + c0 * 2) ^ ((e & 7) << 4);
            *(u16x4*)(sbytes + b) = u;
        }
    __syncthreads();

    // ---- GEMM2: K = 128 (4 chunks)
    #pragma unroll
    for (int ci = 0; ci < 2; ++ci)
        #pragma unroll
        for (int ej = 0; ej < 4; ++ej) acc[ci][ej] = (f32x4){0.f, 0.f, 0.f, 0.f};
    {
        const unsigned short* w0 = Wt2 + (size_t)(cb + lo) * D + hi * 8;
        const unsigned short* w1 = Wt2 + (size_t)(cb + 16 + lo) * D + hi * 8;
        #pragma unroll
        for (int kk = 0; kk < 4; ++kk) {
            bf16x8 a0 = *(const bf16x8*)(w0 + kk * 32);
            bf16x8 a1 = *(const bf16x8*)(w1 + kk * 32);
            bf16x8 bfr[4];
            #pragma unroll
            for (int ej = 0; ej < 4; ++ej) {
                int b = ((16 * ej + lo) * 256 + kk * 64 + hi * 16) ^ ((lo & 7) << 4);
                bfr[ej] = *(const bf16x8*)(sbytes + b);
            }
            #pragma unroll
            for (int ej = 0; ej < 4; ++ej) {
                acc[0][ej] = __builtin_amdgcn_mfma_f32_16x16x32_bf16(a0, bfr[ej], acc[0][ej], 0, 0, 0);
                acc[1][ej] = __builtin_amdgcn_mfma_f32_16x16x32_bf16(a1, bfr[ej], acc[1][ej], 0, 0, 0);
            }
        }
    }
    #pragma unroll
    for (int ci = 0; ci < 2; ++ci)
        #pragma unroll
        for (int r = 0; r < 4; ++r) bv[ci][r] = be2[cb + 16 * ci + hi * 4 + r];

    // ---- m_ij = SiLU(...): write bf16 copy to LDS [16K,32K) + f32 atomics into m_i
    #pragma unroll
    for (int ci = 0; ci < 2; ++ci)
        #pragma unroll
        for (int ej = 0; ej < 4; ++ej) {
            const int e = 16 * ej + lo, c0 = cb + 16 * ci + hi * 4;
            float mv[4];
            u16x4 u;
            #pragma unroll
            for (int r = 0; r < 4; ++r) { mv[r] = silu_f(acc[ci][ej][r] + bv[ci][r]); u[r] = f2bf(mv[r]); }
            int b = 16384 + ((e * 256 + c0 * 2) ^ ((e & 7) << 4));
            *(u16x4*)(sbytes + b) = u;
            float* mp = m_i + (size_t)s_dst[e] * D + c0;
            #pragma unroll
            for (int r = 0; r < 4; ++r) unsafeAtomicAdd(mp + r, mv[r]);
        }
    __syncthreads();

    // ---- GEMM3 (coord MLP layer 1): K = 128
    #pragma unroll
    for (int ci = 0; ci < 2; ++ci)
        #pragma unroll
        for (int ej = 0; ej < 4; ++ej) acc[ci][ej] = (f32x4){0.f, 0.f, 0.f, 0.f};
    {
        const unsigned short* w0 = Wtc1 + (size_t)(cb + lo) * D + hi * 8;
        const unsigned short* w1 = Wtc1 + (size_t)(cb + 16 + lo) * D + hi * 8;
        #pragma unroll
        for (int kk = 0; kk < 4; ++kk) {
            bf16x8 a0 = *(const bf16x8*)(w0 + kk * 32);
            bf16x8 a1 = *(const bf16x8*)(w1 + kk * 32);
            bf16x8 bfr[4];
            #pragma unroll
            for (int ej = 0; ej < 4; ++ej) {
                int b = 16384 + (((16 * ej + lo) * 256 + kk * 64 + hi * 16) ^ ((lo & 7) << 4));
                bfr[ej] = *(const bf16x8*)(sbytes + b);
            }
            #pragma unroll
            for (int ej = 0; ej < 4; ++ej) {
                acc[0][ej] = __builtin_amdgcn_mfma_f32_16x16x32_bf16(a0, bfr[ej], acc[0][ej], 0, 0, 0);
                acc[1][ej] = __builtin_amdgcn_mfma_f32_16x16x32_bf16(a1, bfr[ej], acc[1][ej], 0, 0, 0);
            }
        }
    }
    // per-lane partial dot with Wc2, reduce over the 4 hi-groups, then over waves via LDS
    {
        float wcv[2][4], bcv[2][4];
        #pragma unroll
        for (int ci = 0; ci < 2; ++ci)
            #pragma unroll
            for (int r = 0; r < 4; ++r) {
                const int c = cb + 16 * ci + hi * 4 + r;
                wcv[ci][r] = wc2[c]; bcv[ci][r] = bc1[c];
            }
        float p[4] = {0.f, 0.f, 0.f, 0.f};
        #pragma unroll
        for (int ci = 0; ci < 2; ++ci)
            #pragma unroll
            for (int ej = 0; ej < 4; ++ej)
                #pragma unroll
                for (int r = 0; r < 4; ++r)
                    p[ej] += silu_f(acc[ci][ej][r] + bcv[ci][r]) * wcv[ci][r];
        #pragma unroll
        for (int ej = 0; ej < 4; ++ej) {
            p[ej] += __shfl_xor(p[ej], 16, 64);
            p[ej] += __shfl_xor(p[ej], 32, 64);
        }
        if (hi == 0) {
            #pragma unroll
            for (int ej = 0; ej < 4; ++ej) cwp[w * MT + 16 * ej + lo] = p[ej];
        }
    }
    __syncthreads();
    if (tid < MT) {
        const float cw = cwp[tid] + cwp[MT + tid] + cwp[2 * MT + tid] + cwp[3 * MT + tid];
        const int ge = blk * MT + tid;
        const int s = s_src[tid];
        const float* dc = diff_cart + (size_t)ge * 3;
        unsafeAtomicAdd(coord_out + (size_t)s * 3 + 0, dc[0] * cw);
        unsafeAtomicAdd(coord_out + (size_t)s * 3 + 1, dc[1] * cw);
        unsafeAtomicAdd(coord_out + (size_t)s * 3 + 2, dc[2] * cw);
    }
}

// ---------------------------------------------------------------- node kernel: h + MLP([h|m_i|t_emb])
__global__ __launch_bounds__(256) void node_kernel(
    const float* __restrict__ h, const float* __restrict__ m_i,
    const float* __restrict__ tembn,
    const unsigned short* __restrict__ Wtn1, const float* __restrict__ bn1,
    const unsigned short* __restrict__ Wtn2, const float* __restrict__ bn2,
    float* __restrict__ out)
{
    __shared__ __align__(16) unsigned short smem[MT * KN];  // 49152 B; X overlays [0,16K)
    char* sbytes = (char*)smem;
    const int tid = threadIdx.x, blk = blockIdx.x;
    const int w = tid >> 6, l = tid & 63, lo = l & 15, hi = l >> 4;
    const int cb = w * 32;

    // ---- build A tile
    {
        const int r = tid >> 2, q = tid & 3;
        const int n = blk * MT + r;
        const bool valid = (n < N_NODES);
        const float* hp = h + (size_t)n * D;
        const float* mp = m_i + (size_t)n * D;
        const float* tp = tembn + (size_t)n * T;
        #pragma unroll
        for (int i = 0; i < 12; ++i) {
            const int ch = q * 12 + i, col = ch * 8;
            float vals[8];
            if (valid) {
                const float* p = (col < 128) ? (hp + col) : (col < 256) ? (mp + col - 128) : (tp + col - 256);
                f32x4 v0 = *(const f32x4*)p;
                f32x4 v1 = *(const f32x4*)(p + 4);
                #pragma unroll
                for (int j = 0; j < 4; ++j) { vals[j] = v0[j]; vals[4 + j] = v1[j]; }
            } else {
                #pragma unroll
                for (int j = 0; j < 8; ++j) vals[j] = 0.0f;
            }
            u16x8 u;
            #pragma unroll
            for (int j = 0; j < 8; ++j) u[j] = f2bf(vals[j]);
            int b = (r * (KN * 2) + col * 2) ^ ((r & 7) << 4);
            *(u16x8*)(sbytes + b) = u;
        }
    }
    __syncthreads();

    // ---- GEMM1: K = 384 (12 chunks)
    f32x4 acc[2][4];
    #pragma unroll
    for (int ci = 0; ci < 2; ++ci)
        #pragma unroll
        for (int ej = 0; ej < 4; ++ej) acc[ci][ej] = (f32x4){0.f, 0.f, 0.f, 0.f};
    {
        const unsigned short* w0 = Wtn1 + (size_t)(cb + lo) * KN + hi * 8;
        const unsigned short* w1 = Wtn1 + (size_t)(cb + 16 + lo) * KN + hi * 8;
        #pragma unroll
        for (int kk = 0; kk < 12; ++kk) {
            bf16x8 a0 = *(const bf16x8*)(w0 + kk * 32);
            bf16x8 a1 = *(const bf16x8*)(w1 + kk * 32);
            bf16x8 bfr[4];
            #pragma unroll
            for (int ej = 0; ej < 4; ++ej) {
                int b = ((16 * ej + lo) * (KN * 2) + kk * 64 + hi * 16) ^ ((lo & 7) << 4);
                bfr[ej] = *(const bf16x8*)(sbytes + b);
            }
            #pragma unroll
            for (int ej = 0; ej < 4; ++ej) {
                acc[0][ej] = __builtin_amdgcn_mfma_f32_16x16x32_bf16(a0, bfr[ej], acc[0][ej], 0, 0, 0);
                acc[1][ej] = __builtin_amdgcn_mfma_f32_16x16x32_bf16(a1, bfr[ej], acc[1][ej], 0, 0, 0);
            }
        }
    }
    float bv[2][4];
    #pragma unroll
    for (int ci = 0; ci < 2; ++ci)
        #pragma unroll
        for (int r = 0; r < 4; ++r) bv[ci][r] = bn1[cb + 16 * ci + hi * 4 + r];
    __syncthreads();

    // ---- bias+SiLU -> X
    #pragma unroll
    for (int ci = 0; ci < 2; ++ci)
        #pragma unroll
        for (int ej = 0; ej < 4; ++ej) {
            u16x4 u;
            #pragma unroll
            for (int r = 0; r < 4; ++r) u[r] = f2bf(silu_f(acc[ci][ej][r] + bv[ci][r]));
            const int e = 16 * ej + lo, c0 = cb + 16 * ci + hi * 4;
            int b = (e * 256 + c0 * 2) ^ ((e & 7) << 4);
            *(u16x4*)(sbytes + b) = u;
        }
    __syncthreads();

    // ---- GEMM2: K = 128
    #pragma unroll
    for (int ci = 0; ci < 2; ++ci)
        #pragma unroll
        for (int ej = 0; ej < 4; ++ej) acc[ci][ej] = (f32x4){0.f, 0.f, 0.f, 0.f};
    {
        const unsigned short* w0 = Wtn2 + (size_t)(cb + lo) * D + hi * 8;
        const unsigned short* w1 = Wtn2 + (size_t)(cb + 16 + lo) * D + hi * 8;
        #pragma unroll
        for (int kk = 0; kk < 4; ++kk) {
            bf16x8 a0 = *(const bf16x8*)(w0 + kk * 32);
            bf16x8 a1 = *(const bf16x8*)(w1 + kk * 32);
            bf16x8 bfr[4];
            #pragma unroll
            for (int ej = 0; ej < 4; ++ej) {
                int b = ((16 * ej + lo) * 256 + kk * 64 + hi * 16) ^ ((lo & 7) << 4);
                bfr[ej] = *(const bf16x8*)(sbytes + b);
            }
            #pragma unroll
            for (int ej = 0; ej < 4; ++ej) {
                acc[0][ej] = __builtin_amdgcn_mfma_f32_16x16x32_bf16(a0, bfr[ej], acc[0][ej], 0, 0, 0);
                acc[1][ej] = __builtin_amdgcn_mfma_f32_16x16x32_bf16(a1, bfr[ej], acc[1][ej], 0, 0, 0);
            }
        }
    }
    #pragma unroll
    for (int ci = 0; ci < 2; ++ci)
        #pragma unroll
        for (int r = 0; r < 4; ++r) bv[ci][r] = bn2[cb + 16 * ci + hi * 4 + r];

    // ---- epilogue: + bias + residual, coalesced f32x4 stores
    #pragma unroll
    for (int ej = 0; ej < 4; ++ej) {
        const int e = 16 * ej + lo;
        const int n2 = blk * MT + e;
        if (n2 < N_NODES) {
            #pragma unroll
            for (int ci = 0; ci < 2; ++ci) {
                const int c0 = cb + 16 * ci + hi * 4;
                f32x4 hres = *(const f32x4*)(h + (size_t)n2 * D + c0);
                f32x4 o;
                #pragma unroll
                for (int r = 0; r < 4; ++r) o[r] = acc[ci][ej][r] + bv[ci][r] + hres[r];
                *(f32x4*)(out + (size_t)n2 * D + c0) = o;
            }
        }
    }
}

// ---------------------------------------------------------------- launcher
extern "C" void kernel_launch(void* const* d_in, const int* in_sizes, int n_in,
                              void* d_out, int out_size, void* d_ws, size_t ws_size,
                              hipStream_t stream) {
    const float* h    = (const float*)d_in[0];
    const float* diff = (const float*)d_in[1];
    const float* dsq  = (const float*)d_in[2];
    const int*   esrc = (const int*)d_in[3];
    const int*   edst = (const int*)d_in[4];
    const float* tEe  = (const float*)d_in[5];
    const float* tEn  = (const float*)d_in[6];
    const float* We1  = (const float*)d_in[7];
    const float* be1  = (const float*)d_in[8];
    const float* We2  = (const float*)d_in[9];
    const float* be2  = (const float*)d_in[10];
    const float* Wc1  = (const float*)d_in[11];
    const float* bc1  = (const float*)d_in[12];
    const float* Wc2  = (const float*)d_in[13];
    const float* Wn1  = (const float*)d_in[14];
    const float* bn1  = (const float*)d_in[15];
    const float* Wn2  = (const float*)d_in[16];
    const float* bn2  = (const float*)d_in[17];

    float* out = (float*)d_out;
    float* coord_out = out + (size_t)N_NODES * D;

    char* ws = (char*)d_ws;
    float* m_i = (float*)ws;
    size_t off = (size_t)N_NODES * D * sizeof(float);      // 25,600,000 B (16B aligned)
    unsigned short* Wt1  = (unsigned short*)(ws + off); off += (size_t)D * KE * 2;
    unsigned short* Wt2  = (unsigned short*)(ws + off); off += (size_t)D * D * 2;
    unsigned short* Wtc1 = (unsigned short*)(ws + off); off += (size_t)D * D * 2;
    unsigned short* Wtn1 = (unsigned short*)(ws + off); off += (size_t)D * KN * 2;
    unsigned short* Wtn2 = (unsigned short*)(ws + off); off += (size_t)D * D * 2;

    hipMemsetAsync(m_i, 0, (size_t)N_NODES * D * sizeof(float), stream);
    hipMemsetAsync(coord_out, 0, (size_t)N_NODES * 3 * sizeof(float), stream);

    prep_weights<<<dim3(D), dim3(256), 0, stream>>>(We1, We2, Wc1, Wn1, Wn2,
                                                    Wt1, Wt2, Wtc1, Wtn1, Wtn2);
    edge_kernel<<<dim3(N_EDGES / MT), dim3(256), 0, stream>>>(
        h, diff, dsq, esrc, edst, tEe, Wt1, be1, Wt2, be2, Wtc1, bc1, Wc2, m_i, coord_out);
    node_kernel<<<dim3((N_NODES + MT - 1) / MT), dim3(256), 0, stream>>>(
        h, m_i, tEn, Wtn1, bn1, Wtn2, bn2, out);
}

// Round 2
// 1153.103 us; speedup vs baseline: 1.4850x; 1.4850x over previous
//
#include <hip/hip_runtime.h>
#include <hip/hip_bf16.h>

#define N_NODES 50000
#define N_EDGES 640000
#define D 128
#define T 128
#define KE 384      // edge-MLP K: [h_src 0-127 | h_dst 128-255 | t_emb 256-383]; dist handled as rank-1 VALU update
#define KN 384      // node-MLP K: [h | m_i | t_emb_nodes]
#define MT 64       // rows (edges/nodes) per block

typedef __attribute__((ext_vector_type(8))) short  bf16x8;
typedef __attribute__((ext_vector_type(4))) float  f32x4;
typedef __attribute__((ext_vector_type(4))) unsigned short u16x4;
typedef __attribute__((ext_vector_type(8))) unsigned short u16x8;

__device__ __forceinline__ float silu_f(float x) { return x / (1.0f + __expf(-x)); }

__device__ __forceinline__ unsigned short f2bf(float x) {
    union { float f; unsigned u; } v; v.f = x;
    unsigned r = v.u + 0x7fffu + ((v.u >> 16) & 1u);   // RNE
    return (unsigned short)(r >> 16);
}

__device__ __forceinline__ float bf2f(unsigned short u) {
    union { unsigned u; float f; } v; v.u = ((unsigned)u) << 16;
    return v.f;
}

// ---------------------------------------------------------------- prep: transpose weights -> bf16 [col][k]
__global__ __launch_bounds__(256) void prep_weights(
    const float* __restrict__ We1, const float* __restrict__ We2,
    const float* __restrict__ Wc1, const float* __restrict__ Wn1,
    const float* __restrict__ Wn2,
    unsigned short* __restrict__ Wt1, unsigned short* __restrict__ Wt2,
    unsigned short* __restrict__ Wtc1, unsigned short* __restrict__ Wtn1,
    unsigned short* __restrict__ Wtn2, float* __restrict__ w1dist)
{
    const int c = blockIdx.x;     // output channel 0..127
    const int t = threadIdx.x;
    for (int k = t; k < KE; k += 256) {
        // k<256: h_src|h_dst rows 0..255; k in [256,384): t_emb rows 257..384 (row 256 = dist handled separately)
        float v = (k < 256) ? We1[(size_t)k * D + c] : We1[(size_t)(k + 1) * D + c];
        Wt1[(size_t)c * KE + k] = f2bf(v);
    }
    if (t == 0) w1dist[c] = We1[(size_t)256 * D + c];
    for (int k = t; k < D; k += 256) {
        Wt2 [(size_t)c * D + k] = f2bf(We2[(size_t)k * D + c]);
        Wtc1[(size_t)c * D + k] = f2bf(Wc1[(size_t)k * D + c]);
        Wtn2[(size_t)c * D + k] = f2bf(Wn2[(size_t)k * D + c]);
    }
    for (int k = t; k < KN; k += 256) {
        Wtn1[(size_t)c * KN + k] = f2bf(Wn1[(size_t)k * D + c]);
    }
}

// ---------------------------------------------------------------- CSR build: histogram -> scan -> fill
__global__ __launch_bounds__(256) void hist_kernel(const int* __restrict__ edst, int* __restrict__ cnt) {
    const int i = blockIdx.x * 256 + threadIdx.x;
    if (i < N_EDGES) atomicAdd(&cnt[edst[i]], 1);
}

__global__ __launch_bounds__(1024) void scan_kernel(const int* __restrict__ cnt,
                                                    int* __restrict__ off, int* __restrict__ cur) {
    __shared__ int part[1024];
    const int t = threadIdx.x;
    const int PER = 49;                       // 1024*49 = 50176 >= 50000
    const int base = t * PER;
    int s = 0;
    for (int i = 0; i < PER; ++i) { int idx = base + i; if (idx < N_NODES) s += cnt[idx]; }
    part[t] = s; __syncthreads();
    for (int d = 1; d < 1024; d <<= 1) {
        int v = (t >= d) ? part[t - d] : 0;
        __syncthreads();
        part[t] += v;
        __syncthreads();
    }
    int excl = (t == 0) ? 0 : part[t - 1];
    for (int i = 0; i < PER; ++i) {
        int idx = base + i;
        if (idx < N_NODES) { off[idx] = excl; cur[idx] = excl; excl += cnt[idx]; }
    }
    if (t == 1023) off[N_NODES] = excl;       // = N_EDGES
}

__global__ __launch_bounds__(256) void fill_kernel(const int* __restrict__ edst,
                                                   int* __restrict__ cur, int* __restrict__ eidx) {
    const int i = blockIdx.x * 256 + threadIdx.x;
    if (i < N_EDGES) {
        const int pos = atomicAdd(&cur[edst[i]], 1);
        eidx[pos] = i;
    }
}

// ---------------------------------------------------------------- fused edge kernel
// per block: 64 edges. A-tile (edge_input, bf16, XOR-swizzled) in LDS.
// GEMM operands swapped: mfma(A=W^T frag, B=edge frag) -> lane holds 4 consecutive
// output channels of one edge. m_ij streamed to global (bf16); coords via 1.9M atomics.
__global__ __launch_bounds__(256) void edge_kernel(
    const float* __restrict__ h, const float* __restrict__ diff_cart,
    const float* __restrict__ dist_sq, const int* __restrict__ esrc,
    const int* __restrict__ edst, const float* __restrict__ temb,
    const unsigned short* __restrict__ Wt1, const float* __restrict__ be1,
    const unsigned short* __restrict__ Wt2, const float* __restrict__ be2,
    const unsigned short* __restrict__ Wtc1, const float* __restrict__ bc1,
    const float* __restrict__ wc2, const float* __restrict__ w1dist,
    unsigned short* __restrict__ mij, float* __restrict__ coord_out)
{
    __shared__ __align__(16) unsigned short smem[MT * KE];  // 49152 B; X overlays [0,16K), m_ij at [16K,32K)
    __shared__ float cwp[4 * MT];
    __shared__ int s_src[MT];
    __shared__ float s_dist[MT];

    char* sbytes = (char*)smem;
    const int tid = threadIdx.x, blk = blockIdx.x;
    const int w = tid >> 6, l = tid & 63, lo = l & 15, hi = l >> 4;
    const int cb = w * 32;

    if (tid < MT) {
        s_src[tid]  = esrc[blk * MT + tid];
        s_dist[tid] = dist_sq[blk * MT + tid];
    }

    // ---- build A tile: 4 threads/row, 12 chunks of 8 cols each
    {
        const int r = tid >> 2, q = tid & 3;
        const int ge = blk * MT + r;
        const int src = esrc[ge], dst = edst[ge];
        const float* hs = h + (size_t)src * D;
        const float* hd = h + (size_t)dst * D;
        const float* tp = temb + (size_t)ge * T;
        #pragma unroll
        for (int i = 0; i < 12; ++i) {
            const int col = (q * 12 + i) * 8;
            const float* p = (col < 128) ? (hs + col) : (col < 256) ? (hd + col - 128) : (tp + col - 256);
            f32x4 v0 = *(const f32x4*)p;
            f32x4 v1 = *(const f32x4*)(p + 4);
            u16x8 u;
            #pragma unroll
            for (int j = 0; j < 4; ++j) { u[j] = f2bf(v0[j]); u[4 + j] = f2bf(v1[j]); }
            int b = (r * (KE * 2) + col * 2) ^ ((r & 7) << 4);
            *(u16x8*)(sbytes + b) = u;
        }
    }
    __syncthreads();

    // ---- GEMM1: K = 384 (12 chunks of 32)
    f32x4 acc[2][4];
    #pragma unroll
    for (int ci = 0; ci < 2; ++ci)
        #pragma unroll
        for (int ej = 0; ej < 4; ++ej) acc[ci][ej] = (f32x4){0.f, 0.f, 0.f, 0.f};
    {
        const unsigned short* w0 = Wt1 + (size_t)(cb + lo) * KE + hi * 8;
        const unsigned short* w1 = Wt1 + (size_t)(cb + 16 + lo) * KE + hi * 8;
        #pragma unroll
        for (int kk = 0; kk < 12; ++kk) {
            bf16x8 a0 = *(const bf16x8*)(w0 + kk * 32);
            bf16x8 a1 = *(const bf16x8*)(w1 + kk * 32);
            bf16x8 bfr[4];
            #pragma unroll
            for (int ej = 0; ej < 4; ++ej) {
                int b = ((16 * ej + lo) * (KE * 2) + kk * 64 + hi * 16) ^ ((lo & 7) << 4);
                bfr[ej] = *(const bf16x8*)(sbytes + b);
            }
            #pragma unroll
            for (int ej = 0; ej < 4; ++ej) {
                acc[0][ej] = __builtin_amdgcn_mfma_f32_16x16x32_bf16(a0, bfr[ej], acc[0][ej], 0, 0, 0);
                acc[1][ej] = __builtin_amdgcn_mfma_f32_16x16x32_bf16(a1, bfr[ej], acc[1][ej], 0, 0, 0);
            }
        }
    }
    float bv[2][4], wd[2][4];
    #pragma unroll
    for (int ci = 0; ci < 2; ++ci) {
        f32x4 b4 = *(const f32x4*)(be1 + cb + 16 * ci + hi * 4);
        f32x4 w4 = *(const f32x4*)(w1dist + cb + 16 * ci + hi * 4);
        #pragma unroll
        for (int r = 0; r < 4; ++r) { bv[ci][r] = b4[r]; wd[ci][r] = w4[r]; }
    }
    __syncthreads();   // all A-tile reads done before X overlays it

    // ---- bias + dist rank-1 + SiLU, pack X (bf16) into LDS [0,16K)
    #pragma unroll
    for (int ci = 0; ci < 2; ++ci)
        #pragma unroll
        for (int ej = 0; ej < 4; ++ej) {
            const float dv = s_dist[16 * ej + lo];
            u16x4 u;
            #pragma unroll
            for (int r = 0; r < 4; ++r) u[r] = f2bf(silu_f(acc[ci][ej][r] + bv[ci][r] + dv * wd[ci][r]));
            const int e = 16 * ej + lo, c0 = cb + 16 * ci + hi * 4;
            int b = (e * 256 + c0 * 2) ^ ((e & 7) << 4);
            *(u16x4*)(sbytes + b) = u;
        }
    __syncthreads();

    // ---- GEMM2: K = 128 (4 chunks)
    #pragma unroll
    for (int ci = 0; ci < 2; ++ci)
        #pragma unroll
        for (int ej = 0; ej < 4; ++ej) acc[ci][ej] = (f32x4){0.f, 0.f, 0.f, 0.f};
    {
        const unsigned short* w0 = Wt2 + (size_t)(cb + lo) * D + hi * 8;
        const unsigned short* w1 = Wt2 + (size_t)(cb + 16 + lo) * D + hi * 8;
        #pragma unroll
        for (int kk = 0; kk < 4; ++kk) {
            bf16x8 a0 = *(const bf16x8*)(w0 + kk * 32);
            bf16x8 a1 = *(const bf16x8*)(w1 + kk * 32);
            bf16x8 bfr[4];
            #pragma unroll
            for (int ej = 0; ej < 4; ++ej) {
                int b = ((16 * ej + lo) * 256 + kk * 64 + hi * 16) ^ ((lo & 7) << 4);
                bfr[ej] = *(const bf16x8*)(sbytes + b);
            }
            #pragma unroll
            for (int ej = 0; ej < 4; ++ej) {
                acc[0][ej] = __builtin_amdgcn_mfma_f32_16x16x32_bf16(a0, bfr[ej], acc[0][ej], 0, 0, 0);
                acc[1][ej] = __builtin_amdgcn_mfma_f32_16x16x32_bf16(a1, bfr[ej], acc[1][ej], 0, 0, 0);
            }
        }
    }
    #pragma unroll
    for (int ci = 0; ci < 2; ++ci) {
        f32x4 b4 = *(const f32x4*)(be2 + cb + 16 * ci + hi * 4);
        #pragma unroll
        for (int r = 0; r < 4; ++r) bv[ci][r] = b4[r];
    }

    // ---- m_ij = SiLU(...): write bf16 to LDS [16K,32K)
    #pragma unroll
    for (int ci = 0; ci < 2; ++ci)
        #pragma unroll
        for (int ej = 0; ej < 4; ++ej) {
            const int e = 16 * ej + lo, c0 = cb + 16 * ci + hi * 4;
            u16x4 u;
            #pragma unroll
            for (int r = 0; r < 4; ++r) u[r] = f2bf(silu_f(acc[ci][ej][r] + bv[ci][r]));
            int b = 16384 + ((e * 256 + c0 * 2) ^ ((e & 7) << 4));
            *(u16x4*)(sbytes + b) = u;
        }
    __syncthreads();

    // ---- coalesced stream of m_ij LDS -> global (fire-and-forget)
    {
        const int r = tid >> 2, q = tid & 3;
        unsigned short* gp = mij + (size_t)(blk * MT + r) * D + q * 32;
        #pragma unroll
        for (int i = 0; i < 4; ++i) {
            int b = 16384 + ((r * 256 + q * 64 + i * 16) ^ ((r & 7) << 4));
            *(u16x8*)(gp + i * 8) = *(const u16x8*)(sbytes + b);
        }
    }

    // ---- GEMM3 (coord MLP layer 1): K = 128, reads m_ij LDS
    #pragma unroll
    for (int ci = 0; ci < 2; ++ci)
        #pragma unroll
        for (int ej = 0; ej < 4; ++ej) acc[ci][ej] = (f32x4){0.f, 0.f, 0.f, 0.f};
    {
        const unsigned short* w0 = Wtc1 + (size_t)(cb + lo) * D + hi * 8;
        const unsigned short* w1 = Wtc1 + (size_t)(cb + 16 + lo) * D + hi * 8;
        #pragma unroll
        for (int kk = 0; kk < 4; ++kk) {
            bf16x8 a0 = *(const bf16x8*)(w0 + kk * 32);
            bf16x8 a1 = *(const bf16x8*)(w1 + kk * 32);
            bf16x8 bfr[4];
            #pragma unroll
            for (int ej = 0; ej < 4; ++ej) {
                int b = 16384 + (((16 * ej + lo) * 256 + kk * 64 + hi * 16) ^ ((lo & 7) << 4));
                bfr[ej] = *(const bf16x8*)(sbytes + b);
            }
            #pragma unroll
            for (int ej = 0; ej < 4; ++ej) {
                acc[0][ej] = __builtin_amdgcn_mfma_f32_16x16x32_bf16(a0, bfr[ej], acc[0][ej], 0, 0, 0);
                acc[1][ej] = __builtin_amdgcn_mfma_f32_16x16x32_bf16(a1, bfr[ej], acc[1][ej], 0, 0, 0);
            }
        }
    }
    // per-lane partial dot with Wc2, reduce over hi-groups, then over waves via LDS
    {
        float wcv[2][4], bcv[2][4];
        #pragma unroll
        for (int ci = 0; ci < 2; ++ci) {
            f32x4 w4 = *(const f32x4*)(wc2 + cb + 16 * ci + hi * 4);
            f32x4 b4 = *(const f32x4*)(bc1 + cb + 16 * ci + hi * 4);
            #pragma unroll
            for (int r = 0; r < 4; ++r) { wcv[ci][r] = w4[r]; bcv[ci][r] = b4[r]; }
        }
        float p[4] = {0.f, 0.f, 0.f, 0.f};
        #pragma unroll
        for (int ci = 0; ci < 2; ++ci)
            #pragma unroll
            for (int ej = 0; ej < 4; ++ej)
                #pragma unroll
                for (int r = 0; r < 4; ++r)
                    p[ej] += silu_f(acc[ci][ej][r] + bcv[ci][r]) * wcv[ci][r];
        #pragma unroll
        for (int ej = 0; ej < 4; ++ej) {
            p[ej] += __shfl_xor(p[ej], 16, 64);
            p[ej] += __shfl_xor(p[ej], 32, 64);
        }
        if (hi == 0) {
            #pragma unroll
            for (int ej = 0; ej < 4; ++ej) cwp[w * MT + 16 * ej + lo] = p[ej];
        }
    }
    __syncthreads();
    if (tid < MT) {
        const float cw = cwp[tid] + cwp[MT + tid] + cwp[2 * MT + tid] + cwp[3 * MT + tid];
        const int ge = blk * MT + tid;
        const int s = s_src[tid];
        const float* dc = diff_cart + (size_t)ge * 3;
        unsafeAtomicAdd(coord_out + (size_t)s * 3 + 0, dc[0] * cw);
        unsafeAtomicAdd(coord_out + (size_t)s * 3 + 1, dc[1] * cw);
        unsafeAtomicAdd(coord_out + (size_t)s * 3 + 2, dc[2] * cw);
    }
}

// ---------------------------------------------------------------- node kernel: h + MLP([h | sum_CSR(m_ij) | t_emb])
__global__ __launch_bounds__(256) void node_kernel(
    const float* __restrict__ h, const float* __restrict__ tembn,
    const int* __restrict__ off, const int* __restrict__ eidx,
    const unsigned short* __restrict__ mij,
    const unsigned short* __restrict__ Wtn1, const float* __restrict__ bn1,
    const unsigned short* __restrict__ Wtn2, const float* __restrict__ bn2,
    float* __restrict__ out)
{
    __shared__ __align__(16) unsigned short smem[MT * KN];  // 49152 B; X overlays [0,16K)
    char* sbytes = (char*)smem;
    const int tid = threadIdx.x, blk = blockIdx.x;
    const int w = tid >> 6, l = tid & 63, lo = l & 15, hi = l >> 4;
    const int cb = w * 32;

    // ---- build A tile: 4 threads/row; each thread owns 32 channels of each region
    {
        const int r = tid >> 2, q = tid & 3;
        const int n = blk * MT + r;
        const bool valid = (n < N_NODES);
        // h -> cols [q*32, q*32+32)
        {
            const float* hp = h + (size_t)n * D + q * 32;
            #pragma unroll
            for (int g = 0; g < 4; ++g) {
                u16x8 u;
                if (valid) {
                    f32x4 v0 = *(const f32x4*)(hp + g * 8);
                    f32x4 v1 = *(const f32x4*)(hp + g * 8 + 4);
                    #pragma unroll
                    for (int j = 0; j < 4; ++j) { u[j] = f2bf(v0[j]); u[4 + j] = f2bf(v1[j]); }
                } else {
                    #pragma unroll
                    for (int j = 0; j < 8; ++j) u[j] = 0;
                }
                const int col = q * 32 + g * 8;
                int b = (r * (KN * 2) + col * 2) ^ ((r & 7) << 4);
                *(u16x8*)(sbytes + b) = u;
            }
        }
        // t_emb -> cols [256 + q*32, ...)
        {
            const float* tp = tembn + (size_t)n * T + q * 32;
            #pragma unroll
            for (int g = 0; g < 4; ++g) {
                u16x8 u;
                if (valid) {
                    f32x4 v0 = *(const f32x4*)(tp + g * 8);
                    f32x4 v1 = *(const f32x4*)(tp + g * 8 + 4);
                    #pragma unroll
                    for (int j = 0; j < 4; ++j) { u[j] = f2bf(v0[j]); u[4 + j] = f2bf(v1[j]); }
                } else {
                    #pragma unroll
                    for (int j = 0; j < 8; ++j) u[j] = 0;
                }
                const int col = 256 + q * 32 + g * 8;
                int b = (r * (KN * 2) + col * 2) ^ ((r & 7) << 4);
                *(u16x8*)(sbytes + b) = u;
            }
        }
        // m_i = sum over CSR edges of m_ij (bf16 rows, f32 accum) -> cols [128 + q*32, ...)
        {
            float acc[32];
            #pragma unroll
            for (int j = 0; j < 32; ++j) acc[j] = 0.f;
            const int st = valid ? off[n] : 0;
            const int en = valid ? off[n + 1] : 0;
            for (int j = st; j < en; ++j) {
                const int e = eidx[j];
                const unsigned short* mp = mij + (size_t)e * D + q * 32;
                #pragma unroll
                for (int g = 0; g < 4; ++g) {
                    u16x8 v = *(const u16x8*)(mp + g * 8);
                    #pragma unroll
                    for (int k = 0; k < 8; ++k) acc[g * 8 + k] += bf2f(v[k]);
                }
            }
            #pragma unroll
            for (int g = 0; g < 4; ++g) {
                u16x8 u;
                #pragma unroll
                for (int k = 0; k < 8; ++k) u[k] = f2bf(acc[g * 8 + k]);
                const int col = 128 + q * 32 + g * 8;
                int b = (r * (KN * 2) + col * 2) ^ ((r & 7) << 4);
                *(u16x8*)(sbytes + b) = u;
            }
        }
    }
    __syncthreads();

    // ---- GEMM1: K = 384 (12 chunks)
    f32x4 acc[2][4];
    #pragma unroll
    for (int ci = 0; ci < 2; ++ci)
        #pragma unroll
        for (int ej = 0; ej < 4; ++ej) acc[ci][ej] = (f32x4){0.f, 0.f, 0.f, 0.f};
    {
        const unsigned short* w0 = Wtn1 + (size_t)(cb + lo) * KN + hi * 8;
        const unsigned short* w1 = Wtn1 + (size_t)(cb + 16 + lo) * KN + hi * 8;
        #pragma unroll
        for (int kk = 0; kk < 12; ++kk) {
            bf16x8 a0 = *(const bf16x8*)(w0 + kk * 32);
            bf16x8 a1 = *(const bf16x8*)(w1 + kk * 32);
            bf16x8 bfr[4];
            #pragma unroll
            for (int ej = 0; ej < 4; ++ej) {
                int b = ((16 * ej + lo) * (KN * 2) + kk * 64 + hi * 16) ^ ((lo & 7) << 4);
                bfr[ej] = *(const bf16x8*)(sbytes + b);
            }
            #pragma unroll
            for (int ej = 0; ej < 4; ++ej) {
                acc[0][ej] = __builtin_amdgcn_mfma_f32_16x16x32_bf16(a0, bfr[ej], acc[0][ej], 0, 0, 0);
                acc[1][ej] = __builtin_amdgcn_mfma_f32_16x16x32_bf16(a1, bfr[ej], acc[1][ej], 0, 0, 0);
            }
        }
    }
    float bv[2][4];
    #pragma unroll
    for (int ci = 0; ci < 2; ++ci) {
        f32x4 b4 = *(const f32x4*)(bn1 + cb + 16 * ci + hi * 4);
        #pragma unroll
        for (int r = 0; r < 4; ++r) bv[ci][r] = b4[r];
    }
    __syncthreads();

    // ---- bias+SiLU -> X
    #pragma unroll
    for (int ci = 0; ci < 2; ++ci)
        #pragma unroll
        for (int ej = 0; ej < 4; ++ej) {
            u16x4 u;
            #pragma unroll
            for (int r = 0; r < 4; ++r) u[r] = f2bf(silu_f(acc[ci][ej][r] + bv[ci][r]));
            const int e = 16 * ej + lo, c0 = cb + 16 * ci + hi * 4;
            int b = (e * 256 + c0 * 2) ^ ((e & 7) << 4);
            *(u16x4*)(sbytes + b) = u;
        }
    __syncthreads();

    // ---- GEMM2: K = 128
    #pragma unroll
    for (int ci = 0; ci < 2; ++ci)
        #pragma unroll
        for (int ej = 0; ej < 4; ++ej) acc[ci][ej] = (f32x4){0.f, 0.f, 0.f, 0.f};
    {
        const unsigned short* w0 = Wtn2 + (size_t)(cb + lo) * D + hi * 8;
        const unsigned short* w1 = Wtn2 + (size_t)(cb + 16 + lo) * D + hi * 8;
        #pragma unroll
        for (int kk = 0; kk < 4; ++kk) {
            bf16x8 a0 = *(const bf16x8*)(w0 + kk * 32);
            bf16x8 a1 = *(const bf16x8*)(w1 + kk * 32);
            bf16x8 bfr[4];
            #pragma unroll
            for (int ej = 0; ej < 4; ++ej) {
                int b = ((16 * ej + lo) * 256 + kk * 64 + hi * 16) ^ ((lo & 7) << 4);
                bfr[ej] = *(const bf16x8*)(sbytes + b);
            }
            #pragma unroll
            for (int ej = 0; ej < 4; ++ej) {
                acc[0][ej] = __builtin_amdgcn_mfma_f32_16x16x32_bf16(a0, bfr[ej], acc[0][ej], 0, 0, 0);
                acc[1][ej] = __builtin_amdgcn_mfma_f32_16x16x32_bf16(a1, bfr[ej], acc[1][ej], 0, 0, 0);
            }
        }
    }
    #pragma unroll
    for (int ci = 0; ci < 2; ++ci) {
        f32x4 b4 = *(const f32x4*)(bn2 + cb + 16 * ci + hi * 4);
        #pragma unroll
        for (int r = 0; r < 4; ++r) bv[ci][r] = b4[r];
    }

    // ---- epilogue: + bias + residual, coalesced f32x4 stores
    #pragma unroll
    for (int ej = 0; ej < 4; ++ej) {
        const int e = 16 * ej + lo;
        const int n2 = blk * MT + e;
        if (n2 < N_NODES) {
            #pragma unroll
            for (int ci = 0; ci < 2; ++ci) {
                const int c0 = cb + 16 * ci + hi * 4;
                f32x4 hres = *(const f32x4*)(h + (size_t)n2 * D + c0);
                f32x4 o;
                #pragma unroll
                for (int r = 0; r < 4; ++r) o[r] = acc[ci][ej][r] + bv[ci][r] + hres[r];
                *(f32x4*)(out + (size_t)n2 * D + c0) = o;
            }
        }
    }
}

// ---------------------------------------------------------------- launcher
extern "C" void kernel_launch(void* const* d_in, const int* in_sizes, int n_in,
                              void* d_out, int out_size, void* d_ws, size_t ws_size,
                              hipStream_t stream) {
    const float* h    = (const float*)d_in[0];
    const float* diff = (const float*)d_in[1];
    const float* dsq  = (const float*)d_in[2];
    const int*   esrc = (const int*)d_in[3];
    const int*   edst = (const int*)d_in[4];
    const float* tEe  = (const float*)d_in[5];
    const float* tEn  = (const float*)d_in[6];
    const float* We1  = (const float*)d_in[7];
    const float* be1  = (const float*)d_in[8];
    const float* We2  = (const float*)d_in[9];
    const float* be2  = (const float*)d_in[10];
    const float* Wc1  = (const float*)d_in[11];
    const float* bc1  = (const float*)d_in[12];
    const float* Wc2  = (const float*)d_in[13];
    const float* Wn1  = (const float*)d_in[14];
    const float* bn1  = (const float*)d_in[15];
    const float* Wn2  = (const float*)d_in[16];
    const float* bn2  = (const float*)d_in[17];

    float* out = (float*)d_out;
    float* coord_out = out + (size_t)N_NODES * D;

    char* ws = (char*)d_ws;
    size_t off_b = 0;
    unsigned short* mij = (unsigned short*)(ws + off_b); off_b += (size_t)N_EDGES * D * 2;   // 163.84 MB
    unsigned short* Wt1  = (unsigned short*)(ws + off_b); off_b += (size_t)D * KE * 2;
    unsigned short* Wt2  = (unsigned short*)(ws + off_b); off_b += (size_t)D * D * 2;
    unsigned short* Wtc1 = (unsigned short*)(ws + off_b); off_b += (size_t)D * D * 2;
    unsigned short* Wtn1 = (unsigned short*)(ws + off_b); off_b += (size_t)D * KN * 2;
    unsigned short* Wtn2 = (unsigned short*)(ws + off_b); off_b += (size_t)D * D * 2;
    float* w1dist = (float*)(ws + off_b); off_b += (size_t)D * 4;
    int* cnt  = (int*)(ws + off_b); off_b += (size_t)N_NODES * 4;
    int* csoff= (int*)(ws + off_b); off_b += (size_t)(N_NODES + 1) * 4;
    int* cur  = (int*)(ws + off_b); off_b += (size_t)N_NODES * 4;
    int* eidx = (int*)(ws + off_b); off_b += (size_t)N_EDGES * 4;

    hipMemsetAsync(cnt, 0, (size_t)N_NODES * 4, stream);
    hipMemsetAsync(coord_out, 0, (size_t)N_NODES * 3 * sizeof(float), stream);

    prep_weights<<<dim3(D), dim3(256), 0, stream>>>(We1, We2, Wc1, Wn1, Wn2,
                                                    Wt1, Wt2, Wtc1, Wtn1, Wtn2, w1dist);
    hist_kernel<<<dim3((N_EDGES + 255) / 256), dim3(256), 0, stream>>>(edst, cnt);
    scan_kernel<<<dim3(1), dim3(1024), 0, stream>>>(cnt, csoff, cur);
    fill_kernel<<<dim3((N_EDGES + 255) / 256), dim3(256), 0, stream>>>(edst, cur, eidx);
    edge_kernel<<<dim3(N_EDGES / MT), dim3(256), 0, stream>>>(
        h, diff, dsq, esrc, edst, tEe, Wt1, be1, Wt2, be2, Wtc1, bc1, Wc2, w1dist, mij, coord_out);
    node_kernel<<<dim3((N_NODES + MT - 1) / MT), dim3(256), 0, stream>>>(
        h, tEn, csoff, eidx, mij, Wtn1, bn1, Wtn2, bn2, out);
}

// Round 3
// 1099.219 us; speedup vs baseline: 1.5578x; 1.0490x over previous
//
#include <hip/hip_runtime.h>
#include <hip/hip_bf16.h>

#define N_NODES 50000
#define N_EDGES 640000
#define D 128
#define T 128
#define KE 384      // edge-MLP K: [h_src | h_dst | t_emb]; dist handled as rank-1 VALU update
#define KN 384      // node-MLP K: [h | m_i | t_emb_nodes]
#define MT 64       // rows (edges/nodes) per block

typedef __attribute__((ext_vector_type(8))) short  bf16x8;
typedef __attribute__((ext_vector_type(4))) float  f32x4;
typedef __attribute__((ext_vector_type(2))) unsigned u32x2;
typedef __attribute__((ext_vector_type(4))) unsigned u32x4;

__device__ __forceinline__ float silu_f(float x) { return x / (1.0f + __expf(-x)); }

__device__ __forceinline__ unsigned short f2bf(float x) {
    union { float f; unsigned u; } v; v.f = x;
    unsigned r = v.u + 0x7fffu + ((v.u >> 16) & 1u);   // RNE (prep only)
    return (unsigned short)(r >> 16);
}

__device__ __forceinline__ float bf2f(unsigned short u) {
    union { unsigned u; float f; } v; v.u = ((unsigned)u) << 16;
    return v.f;
}

// packed f32x2 -> bf16x2 (RNE), single HW instr
__device__ __forceinline__ unsigned cvtpk(float a, float b) {
    unsigned r;
    asm("v_cvt_pk_bf16_f32 %0, %1, %2" : "=v"(r) : "v"(a), "v"(b));
    return r;   // lo16 = bf16(a), hi16 = bf16(b)
}

// ---------------------------------------------------------------- prep: transpose weights -> bf16 [col][k]
__global__ __launch_bounds__(256) void prep_weights(
    const float* __restrict__ We1, const float* __restrict__ We2,
    const float* __restrict__ Wc1, const float* __restrict__ Wn1,
    const float* __restrict__ Wn2,
    unsigned short* __restrict__ Wt1, unsigned short* __restrict__ Wt2,
    unsigned short* __restrict__ Wtc1, unsigned short* __restrict__ Wtn1,
    unsigned short* __restrict__ Wtn2, float* __restrict__ w1dist)
{
    const int c = blockIdx.x;     // output channel 0..127
    const int t = threadIdx.x;
    for (int k = t; k < KE; k += 256) {
        float v = (k < 256) ? We1[(size_t)k * D + c] : We1[(size_t)(k + 1) * D + c];
        Wt1[(size_t)c * KE + k] = f2bf(v);
    }
    if (t == 0) w1dist[c] = We1[(size_t)256 * D + c];
    for (int k = t; k < D; k += 256) {
        Wt2 [(size_t)c * D + k] = f2bf(We2[(size_t)k * D + c]);
        Wtc1[(size_t)c * D + k] = f2bf(Wc1[(size_t)k * D + c]);
        Wtn2[(size_t)c * D + k] = f2bf(Wn2[(size_t)k * D + c]);
    }
    for (int k = t; k < KN; k += 256) {
        Wtn1[(size_t)c * KN + k] = f2bf(Wn1[(size_t)k * D + c]);
    }
}

// ---------------------------------------------------------------- CSR build: histogram -> scan -> fill
__global__ __launch_bounds__(256) void hist_kernel(const int* __restrict__ edst, int* __restrict__ cnt) {
    const int i = blockIdx.x * 256 + threadIdx.x;
    if (i < N_EDGES) atomicAdd(&cnt[edst[i]], 1);
}

__global__ __launch_bounds__(1024) void scan_kernel(const int* __restrict__ cnt,
                                                    int* __restrict__ off, int* __restrict__ cur) {
    __shared__ int part[1024];
    const int t = threadIdx.x;
    const int PER = 49;                       // 1024*49 = 50176 >= 50000
    const int base = t * PER;
    int s = 0;
    for (int i = 0; i < PER; ++i) { int idx = base + i; if (idx < N_NODES) s += cnt[idx]; }
    part[t] = s; __syncthreads();
    for (int d = 1; d < 1024; d <<= 1) {
        int v = (t >= d) ? part[t - d] : 0;
        __syncthreads();
        part[t] += v;
        __syncthreads();
    }
    int excl = (t == 0) ? 0 : part[t - 1];
    for (int i = 0; i < PER; ++i) {
        int idx = base + i;
        if (idx < N_NODES) { off[idx] = excl; cur[idx] = excl; excl += cnt[idx]; }
    }
    if (t == 1023) off[N_NODES] = excl;
}

__global__ __launch_bounds__(256) void fill_kernel(const int* __restrict__ edst,
                                                   int* __restrict__ cur, int* __restrict__ eidx) {
    const int i = blockIdx.x * 256 + threadIdx.x;
    if (i < N_EDGES) {
        const int pos = atomicAdd(&cur[edst[i]], 1);
        eidx[pos] = i;
    }
}

// ---------------------------------------------------------------- fused edge kernel (CSR-ordered edges)
// per block: 64 edges sorted by dst. m_ij segment-reduced in LDS -> few atomics into f32 m_i.
__global__ __launch_bounds__(256, 3) void edge_kernel(
    const float* __restrict__ h, const float* __restrict__ diff_cart,
    const float* __restrict__ dist_sq, const int* __restrict__ esrc,
    const int* __restrict__ edst, const float* __restrict__ temb,
    const int* __restrict__ eidx,
    const unsigned short* __restrict__ Wt1, const float* __restrict__ be1,
    const unsigned short* __restrict__ Wt2, const float* __restrict__ be2,
    const unsigned short* __restrict__ Wtc1, const float* __restrict__ bc1,
    const float* __restrict__ wc2, const float* __restrict__ w1dist,
    float* __restrict__ m_i, float* __restrict__ coord_out)
{
    __shared__ __align__(16) unsigned short smem[MT * KE];  // 48KB; X overlays [0,16K), m_ij at [16K,32K)
    __shared__ float cwp[4 * MT];
    __shared__ int s_ge[MT], s_src[MT], s_dst[MT];
    __shared__ float s_dist[MT];

    char* sbytes = (char*)smem;
    const int tid = threadIdx.x, blk = blockIdx.x;
    const int w = tid >> 6, l = tid & 63, lo = l & 15, hi = l >> 4;
    const int cb = w * 32;

    if (tid < MT) {
        const int ge = eidx[blk * MT + tid];
        s_ge[tid]   = ge;
        s_src[tid]  = esrc[ge];
        s_dst[tid]  = edst[ge];
        s_dist[tid] = dist_sq[ge];
    }
    __syncthreads();

    // ---- build A tile: 4 threads/row, 12 chunks of 8 cols each (cvt_pk packing)
    {
        const int r = tid >> 2, q = tid & 3;
        const int ge = s_ge[r];
        const float* hs = h + (size_t)s_src[r] * D;
        const float* hd = h + (size_t)s_dst[r] * D;
        const float* tp = temb + (size_t)ge * T;
        #pragma unroll
        for (int i = 0; i < 12; ++i) {
            const int col = (q * 12 + i) * 8;
            const float* p = (col < 128) ? (hs + col) : (col < 256) ? (hd + col - 128) : (tp + col - 256);
            f32x4 v0 = *(const f32x4*)p;
            f32x4 v1 = *(const f32x4*)(p + 4);
            u32x4 u;
            u[0] = cvtpk(v0[0], v0[1]); u[1] = cvtpk(v0[2], v0[3]);
            u[2] = cvtpk(v1[0], v1[1]); u[3] = cvtpk(v1[2], v1[3]);
            int b = (r * (KE * 2) + col * 2) ^ ((r & 7) << 4);
            *(u32x4*)(sbytes + b) = u;
        }
    }
    __syncthreads();

    // ---- GEMM1: K = 384 (12 chunks of 32)
    f32x4 acc[2][4];
    #pragma unroll
    for (int ci = 0; ci < 2; ++ci)
        #pragma unroll
        for (int ej = 0; ej < 4; ++ej) acc[ci][ej] = (f32x4){0.f, 0.f, 0.f, 0.f};
    {
        const unsigned short* w0 = Wt1 + (size_t)(cb + lo) * KE + hi * 8;
        const unsigned short* w1 = Wt1 + (size_t)(cb + 16 + lo) * KE + hi * 8;
        #pragma unroll
        for (int kk = 0; kk < 12; ++kk) {
            bf16x8 a0 = *(const bf16x8*)(w0 + kk * 32);
            bf16x8 a1 = *(const bf16x8*)(w1 + kk * 32);
            bf16x8 bfr[4];
            #pragma unroll
            for (int ej = 0; ej < 4; ++ej) {
                int b = ((16 * ej + lo) * (KE * 2) + kk * 64 + hi * 16) ^ ((lo & 7) << 4);
                bfr[ej] = *(const bf16x8*)(sbytes + b);
            }
            __builtin_amdgcn_s_setprio(1);
            #pragma unroll
            for (int ej = 0; ej < 4; ++ej) {
                acc[0][ej] = __builtin_amdgcn_mfma_f32_16x16x32_bf16(a0, bfr[ej], acc[0][ej], 0, 0, 0);
                acc[1][ej] = __builtin_amdgcn_mfma_f32_16x16x32_bf16(a1, bfr[ej], acc[1][ej], 0, 0, 0);
            }
            __builtin_amdgcn_s_setprio(0);
        }
    }
    // preload GEMM2 weights (hide L2 latency under pack + barrier)
    bf16x8 w2a[4], w2b[4];
    {
        const unsigned short* p0 = Wt2 + (size_t)(cb + lo) * D + hi * 8;
        const unsigned short* p1 = Wt2 + (size_t)(cb + 16 + lo) * D + hi * 8;
        #pragma unroll
        for (int kk = 0; kk < 4; ++kk) { w2a[kk] = *(const bf16x8*)(p0 + kk * 32); w2b[kk] = *(const bf16x8*)(p1 + kk * 32); }
    }
    float bv[2][4], wd[2][4];
    #pragma unroll
    for (int ci = 0; ci < 2; ++ci) {
        f32x4 b4 = *(const f32x4*)(be1 + cb + 16 * ci + hi * 4);
        f32x4 w4 = *(const f32x4*)(w1dist + cb + 16 * ci + hi * 4);
        #pragma unroll
        for (int r = 0; r < 4; ++r) { bv[ci][r] = b4[r]; wd[ci][r] = w4[r]; }
    }
    __syncthreads();   // all A-tile reads done before X overlays it

    // ---- bias + dist rank-1 + SiLU, pack X (bf16) into LDS [0,16K)
    #pragma unroll
    for (int ci = 0; ci < 2; ++ci)
        #pragma unroll
        for (int ej = 0; ej < 4; ++ej) {
            const float dv = s_dist[16 * ej + lo];
            float s0 = silu_f(acc[ci][ej][0] + bv[ci][0] + dv * wd[ci][0]);
            float s1 = silu_f(acc[ci][ej][1] + bv[ci][1] + dv * wd[ci][1]);
            float s2 = silu_f(acc[ci][ej][2] + bv[ci][2] + dv * wd[ci][2]);
            float s3 = silu_f(acc[ci][ej][3] + bv[ci][3] + dv * wd[ci][3]);
            u32x2 u; u[0] = cvtpk(s0, s1); u[1] = cvtpk(s2, s3);
            const int e = 16 * ej + lo, c0 = cb + 16 * ci + hi * 4;
            int b = (e * 256 + c0 * 2) ^ ((e & 7) << 4);
            *(u32x2*)(sbytes + b) = u;
        }
    __syncthreads();

    // ---- GEMM2: K = 128 (4 chunks, weights in regs)
    #pragma unroll
    for (int ci = 0; ci < 2; ++ci)
        #pragma unroll
        for (int ej = 0; ej < 4; ++ej) acc[ci][ej] = (f32x4){0.f, 0.f, 0.f, 0.f};
    {
        #pragma unroll
        for (int kk = 0; kk < 4; ++kk) {
            bf16x8 bfr[4];
            #pragma unroll
            for (int ej = 0; ej < 4; ++ej) {
                int b = ((16 * ej + lo) * 256 + kk * 64 + hi * 16) ^ ((lo & 7) << 4);
                bfr[ej] = *(const bf16x8*)(sbytes + b);
            }
            __builtin_amdgcn_s_setprio(1);
            #pragma unroll
            for (int ej = 0; ej < 4; ++ej) {
                acc[0][ej] = __builtin_amdgcn_mfma_f32_16x16x32_bf16(w2a[kk], bfr[ej], acc[0][ej], 0, 0, 0);
                acc[1][ej] = __builtin_amdgcn_mfma_f32_16x16x32_bf16(w2b[kk], bfr[ej], acc[1][ej], 0, 0, 0);
            }
            __builtin_amdgcn_s_setprio(0);
        }
    }
    // preload GEMM3 weights
    bf16x8 w3a[4], w3b[4];
    {
        const unsigned short* p0 = Wtc1 + (size_t)(cb + lo) * D + hi * 8;
        const unsigned short* p1 = Wtc1 + (size_t)(cb + 16 + lo) * D + hi * 8;
        #pragma unroll
        for (int kk = 0; kk < 4; ++kk) { w3a[kk] = *(const bf16x8*)(p0 + kk * 32); w3b[kk] = *(const bf16x8*)(p1 + kk * 32); }
    }
    #pragma unroll
    for (int ci = 0; ci < 2; ++ci) {
        f32x4 b4 = *(const f32x4*)(be2 + cb + 16 * ci + hi * 4);
        #pragma unroll
        for (int r = 0; r < 4; ++r) bv[ci][r] = b4[r];
    }

    // ---- m_ij = SiLU(...): write bf16 to LDS [16K,32K)
    #pragma unroll
    for (int ci = 0; ci < 2; ++ci)
        #pragma unroll
        for (int ej = 0; ej < 4; ++ej) {
            const int e = 16 * ej + lo, c0 = cb + 16 * ci + hi * 4;
            float s0 = silu_f(acc[ci][ej][0] + bv[ci][0]);
            float s1 = silu_f(acc[ci][ej][1] + bv[ci][1]);
            float s2 = silu_f(acc[ci][ej][2] + bv[ci][2]);
            float s3 = silu_f(acc[ci][ej][3] + bv[ci][3]);
            u32x2 u; u[0] = cvtpk(s0, s1); u[1] = cvtpk(s2, s3);
            int b = 16384 + ((e * 256 + c0 * 2) ^ ((e & 7) << 4));
            *(u32x2*)(sbytes + b) = u;
        }
    __syncthreads();

    // ---- GEMM3 (coord MLP layer 1): K = 128, reads m_ij LDS (weights in regs)
    #pragma unroll
    for (int ci = 0; ci < 2; ++ci)
        #pragma unroll
        for (int ej = 0; ej < 4; ++ej) acc[ci][ej] = (f32x4){0.f, 0.f, 0.f, 0.f};
    {
        #pragma unroll
        for (int kk = 0; kk < 4; ++kk) {
            bf16x8 bfr[4];
            #pragma unroll
            for (int ej = 0; ej < 4; ++ej) {
                int b = 16384 + (((16 * ej + lo) * 256 + kk * 64 + hi * 16) ^ ((lo & 7) << 4));
                bfr[ej] = *(const bf16x8*)(sbytes + b);
            }
            __builtin_amdgcn_s_setprio(1);
            #pragma unroll
            for (int ej = 0; ej < 4; ++ej) {
                acc[0][ej] = __builtin_amdgcn_mfma_f32_16x16x32_bf16(w3a[kk], bfr[ej], acc[0][ej], 0, 0, 0);
                acc[1][ej] = __builtin_amdgcn_mfma_f32_16x16x32_bf16(w3b[kk], bfr[ej], acc[1][ej], 0, 0, 0);
            }
            __builtin_amdgcn_s_setprio(0);
        }
    }

    // ---- segmented reduction of m_ij (CSR-sorted dst) -> atomics into f32 m_i
    {
        const int c = tid & 127;          // channel
        const int rbase = (tid >> 7) * 32;
        float accr = 0.f;
        int dprev = s_dst[rbase];
        #pragma unroll 8
        for (int i = 0; i < 32; ++i) {
            const int r = rbase + i;
            const int d = s_dst[r];
            if (d != dprev) {
                unsafeAtomicAdd(m_i + (size_t)dprev * D + c, accr);
                accr = 0.f; dprev = d;
            }
            int b = 16384 + ((r * 256 + c * 2) ^ ((r & 7) << 4));
            accr += bf2f(*(const unsigned short*)(sbytes + b));
        }
        unsafeAtomicAdd(m_i + (size_t)dprev * D + c, accr);
    }

    // ---- per-lane partial dot with Wc2, reduce over hi-groups, then over waves via LDS
    {
        float wcv[2][4], bcv[2][4];
        #pragma unroll
        for (int ci = 0; ci < 2; ++ci) {
            f32x4 w4 = *(const f32x4*)(wc2 + cb + 16 * ci + hi * 4);
            f32x4 b4 = *(const f32x4*)(bc1 + cb + 16 * ci + hi * 4);
            #pragma unroll
            for (int r = 0; r < 4; ++r) { wcv[ci][r] = w4[r]; bcv[ci][r] = b4[r]; }
        }
        float p[4] = {0.f, 0.f, 0.f, 0.f};
        #pragma unroll
        for (int ci = 0; ci < 2; ++ci)
            #pragma unroll
            for (int ej = 0; ej < 4; ++ej)
                #pragma unroll
                for (int r = 0; r < 4; ++r)
                    p[ej] += silu_f(acc[ci][ej][r] + bcv[ci][r]) * wcv[ci][r];
        #pragma unroll
        for (int ej = 0; ej < 4; ++ej) {
            p[ej] += __shfl_xor(p[ej], 16, 64);
            p[ej] += __shfl_xor(p[ej], 32, 64);
        }
        if (hi == 0) {
            #pragma unroll
            for (int ej = 0; ej < 4; ++ej) cwp[w * MT + 16 * ej + lo] = p[ej];
        }
    }
    __syncthreads();
    if (tid < MT) {
        const float cw = cwp[tid] + cwp[MT + tid] + cwp[2 * MT + tid] + cwp[3 * MT + tid];
        const int ge = s_ge[tid];
        const int s = s_src[tid];
        const float* dc = diff_cart + (size_t)ge * 3;
        unsafeAtomicAdd(coord_out + (size_t)s * 3 + 0, dc[0] * cw);
        unsafeAtomicAdd(coord_out + (size_t)s * 3 + 1, dc[1] * cw);
        unsafeAtomicAdd(coord_out + (size_t)s * 3 + 2, dc[2] * cw);
    }
}

// ---------------------------------------------------------------- node kernel: h + MLP([h | m_i | t_emb])
__global__ __launch_bounds__(256, 3) void node_kernel(
    const float* __restrict__ h, const float* __restrict__ m_i,
    const float* __restrict__ tembn,
    const unsigned short* __restrict__ Wtn1, const float* __restrict__ bn1,
    const unsigned short* __restrict__ Wtn2, const float* __restrict__ bn2,
    float* __restrict__ out)
{
    __shared__ __align__(16) unsigned short smem[MT * KN];  // 48KB; X overlays [0,16K)
    char* sbytes = (char*)smem;
    const int tid = threadIdx.x, blk = blockIdx.x;
    const int w = tid >> 6, l = tid & 63, lo = l & 15, hi = l >> 4;
    const int cb = w * 32;

    // ---- build A tile
    {
        const int r = tid >> 2, q = tid & 3;
        const int n = blk * MT + r;
        const bool valid = (n < N_NODES);
        const float* hp = h + (size_t)n * D;
        const float* mp = m_i + (size_t)n * D;
        const float* tp = tembn + (size_t)n * T;
        #pragma unroll
        for (int i = 0; i < 12; ++i) {
            const int col = (q * 12 + i) * 8;
            u32x4 u;
            if (valid) {
                const float* p = (col < 128) ? (hp + col) : (col < 256) ? (mp + col - 128) : (tp + col - 256);
                f32x4 v0 = *(const f32x4*)p;
                f32x4 v1 = *(const f32x4*)(p + 4);
                u[0] = cvtpk(v0[0], v0[1]); u[1] = cvtpk(v0[2], v0[3]);
                u[2] = cvtpk(v1[0], v1[1]); u[3] = cvtpk(v1[2], v1[3]);
            } else {
                u[0] = u[1] = u[2] = u[3] = 0u;
            }
            int b = (r * (KN * 2) + col * 2) ^ ((r & 7) << 4);
            *(u32x4*)(sbytes + b) = u;
        }
    }
    __syncthreads();

    // ---- GEMM1: K = 384 (12 chunks)
    f32x4 acc[2][4];
    #pragma unroll
    for (int ci = 0; ci < 2; ++ci)
        #pragma unroll
        for (int ej = 0; ej < 4; ++ej) acc[ci][ej] = (f32x4){0.f, 0.f, 0.f, 0.f};
    {
        const unsigned short* w0 = Wtn1 + (size_t)(cb + lo) * KN + hi * 8;
        const unsigned short* w1 = Wtn1 + (size_t)(cb + 16 + lo) * KN + hi * 8;
        #pragma unroll
        for (int kk = 0; kk < 12; ++kk) {
            bf16x8 a0 = *(const bf16x8*)(w0 + kk * 32);
            bf16x8 a1 = *(const bf16x8*)(w1 + kk * 32);
            bf16x8 bfr[4];
            #pragma unroll
            for (int ej = 0; ej < 4; ++ej) {
                int b = ((16 * ej + lo) * (KN * 2) + kk * 64 + hi * 16) ^ ((lo & 7) << 4);
                bfr[ej] = *(const bf16x8*)(sbytes + b);
            }
            __builtin_amdgcn_s_setprio(1);
            #pragma unroll
            for (int ej = 0; ej < 4; ++ej) {
                acc[0][ej] = __builtin_amdgcn_mfma_f32_16x16x32_bf16(a0, bfr[ej], acc[0][ej], 0, 0, 0);
                acc[1][ej] = __builtin_amdgcn_mfma_f32_16x16x32_bf16(a1, bfr[ej], acc[1][ej], 0, 0, 0);
            }
            __builtin_amdgcn_s_setprio(0);
        }
    }
    // preload GEMM2 weights
    bf16x8 w2a[4], w2b[4];
    {
        const unsigned short* p0 = Wtn2 + (size_t)(cb + lo) * D + hi * 8;
        const unsigned short* p1 = Wtn2 + (size_t)(cb + 16 + lo) * D + hi * 8;
        #pragma unroll
        for (int kk = 0; kk < 4; ++kk) { w2a[kk] = *(const bf16x8*)(p0 + kk * 32); w2b[kk] = *(const bf16x8*)(p1 + kk * 32); }
    }
    float bv[2][4];
    #pragma unroll
    for (int ci = 0; ci < 2; ++ci) {
        f32x4 b4 = *(const f32x4*)(bn1 + cb + 16 * ci + hi * 4);
        #pragma unroll
        for (int r = 0; r < 4; ++r) bv[ci][r] = b4[r];
    }
    __syncthreads();

    // ---- bias+SiLU -> X
    #pragma unroll
    for (int ci = 0; ci < 2; ++ci)
        #pragma unroll
        for (int ej = 0; ej < 4; ++ej) {
            float s0 = silu_f(acc[ci][ej][0] + bv[ci][0]);
            float s1 = silu_f(acc[ci][ej][1] + bv[ci][1]);
            float s2 = silu_f(acc[ci][ej][2] + bv[ci][2]);
            float s3 = silu_f(acc[ci][ej][3] + bv[ci][3]);
            u32x2 u; u[0] = cvtpk(s0, s1); u[1] = cvtpk(s2, s3);
            const int e = 16 * ej + lo, c0 = cb + 16 * ci + hi * 4;
            int b = (e * 256 + c0 * 2) ^ ((e & 7) << 4);
            *(u32x2*)(sbytes + b) = u;
        }
    __syncthreads();

    // ---- GEMM2: K = 128 (weights in regs)
    #pragma unroll
    for (int ci = 0; ci < 2; ++ci)
        #pragma unroll
        for (int ej = 0; ej < 4; ++ej) acc[ci][ej] = (f32x4){0.f, 0.f, 0.f, 0.f};
    {
        #pragma unroll
        for (int kk = 0; kk < 4; ++kk) {
            bf16x8 bfr[4];
            #pragma unroll
            for (int ej = 0; ej < 4; ++ej) {
                int b = ((16 * ej + lo) * 256 + kk * 64 + hi * 16) ^ ((lo & 7) << 4);
                bfr[ej] = *(const bf16x8*)(sbytes + b);
            }
            __builtin_amdgcn_s_setprio(1);
            #pragma unroll
            for (int ej = 0; ej < 4; ++ej) {
                acc[0][ej] = __builtin_amdgcn_mfma_f32_16x16x32_bf16(w2a[kk], bfr[ej], acc[0][ej], 0, 0, 0);
                acc[1][ej] = __builtin_amdgcn_mfma_f32_16x16x32_bf16(w2b[kk], bfr[ej], acc[1][ej], 0, 0, 0);
            }
            __builtin_amdgcn_s_setprio(0);
        }
    }
    #pragma unroll
    for (int ci = 0; ci < 2; ++ci) {
        f32x4 b4 = *(const f32x4*)(bn2 + cb + 16 * ci + hi * 4);
        #pragma unroll
        for (int r = 0; r < 4; ++r) bv[ci][r] = b4[r];
    }

    // ---- epilogue: + bias + residual, coalesced f32x4 stores
    #pragma unroll
    for (int ej = 0; ej < 4; ++ej) {
        const int e = 16 * ej + lo;
        const int n2 = blk * MT + e;
        if (n2 < N_NODES) {
            #pragma unroll
            for (int ci = 0; ci < 2; ++ci) {
                const int c0 = cb + 16 * ci + hi * 4;
                f32x4 hres = *(const f32x4*)(h + (size_t)n2 * D + c0);
                f32x4 o;
                #pragma unroll
                for (int r = 0; r < 4; ++r) o[r] = acc[ci][ej][r] + bv[ci][r] + hres[r];
                *(f32x4*)(out + (size_t)n2 * D + c0) = o;
            }
        }
    }
}

// ---------------------------------------------------------------- launcher
extern "C" void kernel_launch(void* const* d_in, const int* in_sizes, int n_in,
                              void* d_out, int out_size, void* d_ws, size_t ws_size,
                              hipStream_t stream) {
    const float* h    = (const float*)d_in[0];
    const float* diff = (const float*)d_in[1];
    const float* dsq  = (const float*)d_in[2];
    const int*   esrc = (const int*)d_in[3];
    const int*   edst = (const int*)d_in[4];
    const float* tEe  = (const float*)d_in[5];
    const float* tEn  = (const float*)d_in[6];
    const float* We1  = (const float*)d_in[7];
    const float* be1  = (const float*)d_in[8];
    const float* We2  = (const float*)d_in[9];
    const float* be2  = (const float*)d_in[10];
    const float* Wc1  = (const float*)d_in[11];
    const float* bc1  = (const float*)d_in[12];
    const float* Wc2  = (const float*)d_in[13];
    const float* Wn1  = (const float*)d_in[14];
    const float* bn1  = (const float*)d_in[15];
    const float* Wn2  = (const float*)d_in[16];
    const float* bn2  = (const float*)d_in[17];

    float* out = (float*)d_out;
    float* coord_out = out + (size_t)N_NODES * D;

    char* ws = (char*)d_ws;
    size_t off_b = 0;
    float* m_i = (float*)(ws + off_b); off_b += (size_t)N_NODES * D * 4;   // 25.6 MB
    unsigned short* Wt1  = (unsigned short*)(ws + off_b); off_b += (size_t)D * KE * 2;
    unsigned short* Wt2  = (unsigned short*)(ws + off_b); off_b += (size_t)D * D * 2;
    unsigned short* Wtc1 = (unsigned short*)(ws + off_b); off_b += (size_t)D * D * 2;
    unsigned short* Wtn1 = (unsigned short*)(ws + off_b); off_b += (size_t)D * KN * 2;
    unsigned short* Wtn2 = (unsigned short*)(ws + off_b); off_b += (size_t)D * D * 2;
    float* w1dist = (float*)(ws + off_b); off_b += (size_t)D * 4;
    int* cnt  = (int*)(ws + off_b); off_b += (size_t)N_NODES * 4;
    int* csoff= (int*)(ws + off_b); off_b += (size_t)(N_NODES + 1) * 4;
    int* cur  = (int*)(ws + off_b); off_b += (size_t)N_NODES * 4;
    int* eidx = (int*)(ws + off_b); off_b += (size_t)N_EDGES * 4;

    hipMemsetAsync(cnt, 0, (size_t)N_NODES * 4, stream);
    hipMemsetAsync(m_i, 0, (size_t)N_NODES * D * 4, stream);
    hipMemsetAsync(coord_out, 0, (size_t)N_NODES * 3 * sizeof(float), stream);

    prep_weights<<<dim3(D), dim3(256), 0, stream>>>(We1, We2, Wc1, Wn1, Wn2,
                                                    Wt1, Wt2, Wtc1, Wtn1, Wtn2, w1dist);
    hist_kernel<<<dim3((N_EDGES + 255) / 256), dim3(256), 0, stream>>>(edst, cnt);
    scan_kernel<<<dim3(1), dim3(1024), 0, stream>>>(cnt, csoff, cur);
    fill_kernel<<<dim3((N_EDGES + 255) / 256), dim3(256), 0, stream>>>(edst, cur, eidx);
    edge_kernel<<<dim3(N_EDGES / MT), dim3(256), 0, stream>>>(
        h, diff, dsq, esrc, edst, tEe, eidx, Wt1, be1, Wt2, be2, Wtc1, bc1, Wc2, w1dist, m_i, coord_out);
    node_kernel<<<dim3((N_NODES + MT - 1) / MT), dim3(256), 0, stream>>>(
        h, m_i, tEn, Wtn1, bn1, Wtn2, bn2, out);
}

// Round 7
// 1052.113 us; speedup vs baseline: 1.6276x; 1.0448x over previous
//
#include <hip/hip_runtime.h>
#include <hip/hip_bf16.h>

#define N_NODES 50000
#define N_EDGES 640000
#define D 128
#define T 128
#define KE 384      // edge-MLP K: [h_src | h_dst | t_emb]; dist handled as rank-1 VALU update
#define KN 384      // node-MLP K: [h | m_i | t_emb_nodes]
#define MT 64       // rows (edges/nodes) per block

typedef __attribute__((ext_vector_type(8))) short  bf16x8;
typedef __attribute__((ext_vector_type(4))) float  f32x4;
typedef __attribute__((ext_vector_type(2))) unsigned u32x2;
typedef __attribute__((ext_vector_type(4))) unsigned u32x4;

__device__ __forceinline__ float silu_f(float x) { return x / (1.0f + __expf(-x)); }

__device__ __forceinline__ unsigned short f2bf(float x) {
    union { float f; unsigned u; } v; v.f = x;
    unsigned r = v.u + 0x7fffu + ((v.u >> 16) & 1u);   // RNE (prep only)
    return (unsigned short)(r >> 16);
}

__device__ __forceinline__ float bf2f(unsigned short u) {
    union { unsigned u; float f; } v; v.u = ((unsigned)u) << 16;
    return v.f;
}

// packed f32x2 -> bf16x2 (RNE), single HW instr
__device__ __forceinline__ unsigned cvtpk(float a, float b) {
    unsigned r;
    asm("v_cvt_pk_bf16_f32 %0, %1, %2" : "=v"(r) : "v"(a), "v"(b));
    return r;   // lo16 = bf16(a), hi16 = bf16(b)
}

// ---------------------------------------------------------------- prep: transpose weights -> bf16 [col][k]
__global__ __launch_bounds__(256) void prep_weights(
    const float* __restrict__ We1, const float* __restrict__ We2,
    const float* __restrict__ Wc1, const float* __restrict__ Wn1,
    const float* __restrict__ Wn2,
    unsigned short* __restrict__ Wt1, unsigned short* __restrict__ Wt2,
    unsigned short* __restrict__ Wtc1, unsigned short* __restrict__ Wtn1,
    unsigned short* __restrict__ Wtn2, float* __restrict__ w1dist)
{
    const int c = blockIdx.x;     // output channel 0..127
    const int t = threadIdx.x;
    for (int k = t; k < KE; k += 256) {
        float v = (k < 256) ? We1[(size_t)k * D + c] : We1[(size_t)(k + 1) * D + c];
        Wt1[(size_t)c * KE + k] = f2bf(v);
    }
    if (t == 0) w1dist[c] = We1[(size_t)256 * D + c];
    for (int k = t; k < D; k += 256) {
        Wt2 [(size_t)c * D + k] = f2bf(We2[(size_t)k * D + c]);
        Wtc1[(size_t)c * D + k] = f2bf(Wc1[(size_t)k * D + c]);
        Wtn2[(size_t)c * D + k] = f2bf(Wn2[(size_t)k * D + c]);
    }
    for (int k = t; k < KN; k += 256) {
        Wtn1[(size_t)c * KN + k] = f2bf(Wn1[(size_t)k * D + c]);
    }
}

// ---------------------------------------------------------------- CSR build: histogram -> scan -> fill
__global__ __launch_bounds__(256) void hist_kernel(const int* __restrict__ edst, int* __restrict__ cnt) {
    const int i = blockIdx.x * 256 + threadIdx.x;
    if (i < N_EDGES) atomicAdd(&cnt[edst[i]], 1);
}

__global__ __launch_bounds__(1024) void scan_kernel(const int* __restrict__ cnt,
                                                    int* __restrict__ off, int* __restrict__ cur) {
    __shared__ int part[1024];
    const int t = threadIdx.x;
    const int PER = 49;                       // 1024*49 = 50176 >= 50000
    const int base = t * PER;
    int s = 0;
    for (int i = 0; i < PER; ++i) { int idx = base + i; if (idx < N_NODES) s += cnt[idx]; }
    part[t] = s; __syncthreads();
    for (int d = 1; d < 1024; d <<= 1) {
        int v = (t >= d) ? part[t - d] : 0;
        __syncthreads();
        part[t] += v;
        __syncthreads();
    }
    int excl = (t == 0) ? 0 : part[t - 1];
    for (int i = 0; i < PER; ++i) {
        int idx = base + i;
        if (idx < N_NODES) { off[idx] = excl; cur[idx] = excl; excl += cnt[idx]; }
    }
    if (t == 1023) off[N_NODES] = excl;
}

__global__ __launch_bounds__(256) void fill_kernel(const int* __restrict__ edst,
                                                   int* __restrict__ cur, int* __restrict__ eidx) {
    const int i = blockIdx.x * 256 + threadIdx.x;
    if (i < N_EDGES) {
        const int pos = atomicAdd(&cur[edst[i]], 1);
        eidx[pos] = i;
    }
}

// ---------------------------------------------------------------- fused edge kernel (CSR-ordered edges)
// per block: 64 edges sorted by dst. m_ij segment-reduced in LDS -> few atomics into f32 m_i.
__global__ __launch_bounds__(256, 3) void edge_kernel(
    const float* __restrict__ h, const float* __restrict__ diff_cart,
    const float* __restrict__ dist_sq, const int* __restrict__ esrc,
    const int* __restrict__ edst, const float* __restrict__ temb,
    const int* __restrict__ eidx,
    const unsigned short* __restrict__ Wt1, const float* __restrict__ be1,
    const unsigned short* __restrict__ Wt2, const float* __restrict__ be2,
    const unsigned short* __restrict__ Wtc1, const float* __restrict__ bc1,
    const float* __restrict__ wc2, const float* __restrict__ w1dist,
    float* __restrict__ m_i, float* __restrict__ coord_out)
{
    __shared__ __align__(16) unsigned short smem[MT * KE];  // 48KB; X overlays [0,16K), m_ij at [16K,32K)
    __shared__ float cwp[4 * MT];
    __shared__ int s_ge[MT], s_src[MT], s_dst[MT];
    __shared__ float s_dist[MT];

    char* sbytes = (char*)smem;
    const int tid = threadIdx.x, blk = blockIdx.x;
    const int w = tid >> 6, l = tid & 63, lo = l & 15, hi = l >> 4;
    const int cb = w * 32;

    if (tid < MT) {
        const int ge = eidx[blk * MT + tid];
        s_ge[tid]   = ge;
        s_src[tid]  = esrc[ge];
        s_dst[tid]  = edst[ge];
        s_dist[tid] = dist_sq[ge];
    }
    __syncthreads();

    // ---- build A tile: 4 threads/row; ISSUE all 12 loads first (keep in flight), then cvt+write
    {
        const int r = tid >> 2, q = tid & 3;
        const int ge = s_ge[r];
        const float* hs = h + (size_t)s_src[r] * D;
        const float* hd = h + (size_t)s_dst[r] * D;
        const float* tp = temb + (size_t)ge * T;
        f32x4 va[12][2];
        #pragma unroll
        for (int i = 0; i < 12; ++i) {
            const int col = (q * 12 + i) * 8;
            const float* p = (col < 128) ? (hs + col) : (col < 256) ? (hd + col - 128) : (tp + col - 256);
            va[i][0] = *(const f32x4*)p;
            va[i][1] = *(const f32x4*)(p + 4);
        }
        #pragma unroll
        for (int i = 0; i < 12; ++i) {
            const int col = (q * 12 + i) * 8;
            u32x4 u;
            u[0] = cvtpk(va[i][0][0], va[i][0][1]); u[1] = cvtpk(va[i][0][2], va[i][0][3]);
            u[2] = cvtpk(va[i][1][0], va[i][1][1]); u[3] = cvtpk(va[i][1][2], va[i][1][3]);
            int b = (r * (KE * 2) + col * 2) ^ ((r & 7) << 4);
            *(u32x4*)(sbytes + b) = u;
        }
    }
    __syncthreads();

    // ---- GEMM1: K = 384 (12 chunks of 32)
    f32x4 acc[2][4];
    #pragma unroll
    for (int ci = 0; ci < 2; ++ci)
        #pragma unroll
        for (int ej = 0; ej < 4; ++ej) acc[ci][ej] = (f32x4){0.f, 0.f, 0.f, 0.f};
    {
        const unsigned short* w0 = Wt1 + (size_t)(cb + lo) * KE + hi * 8;
        const unsigned short* w1 = Wt1 + (size_t)(cb + 16 + lo) * KE + hi * 8;
        #pragma unroll
        for (int kk = 0; kk < 12; ++kk) {
            bf16x8 a0 = *(const bf16x8*)(w0 + kk * 32);
            bf16x8 a1 = *(const bf16x8*)(w1 + kk * 32);
            bf16x8 bfr[4];
            #pragma unroll
            for (int ej = 0; ej < 4; ++ej) {
                int b = ((16 * ej + lo) * (KE * 2) + kk * 64 + hi * 16) ^ ((lo & 7) << 4);
                bfr[ej] = *(const bf16x8*)(sbytes + b);
            }
            #pragma unroll
            for (int ej = 0; ej < 4; ++ej) {
                acc[0][ej] = __builtin_amdgcn_mfma_f32_16x16x32_bf16(a0, bfr[ej], acc[0][ej], 0, 0, 0);
                acc[1][ej] = __builtin_amdgcn_mfma_f32_16x16x32_bf16(a1, bfr[ej], acc[1][ej], 0, 0, 0);
            }
        }
    }
    // preload GEMM2 weights (hide L2 latency under pack + barrier)
    bf16x8 w2a[4], w2b[4];
    {
        const unsigned short* p0 = Wt2 + (size_t)(cb + lo) * D + hi * 8;
        const unsigned short* p1 = Wt2 + (size_t)(cb + 16 + lo) * D + hi * 8;
        #pragma unroll
        for (int kk = 0; kk < 4; ++kk) { w2a[kk] = *(const bf16x8*)(p0 + kk * 32); w2b[kk] = *(const bf16x8*)(p1 + kk * 32); }
    }
    float bv[2][4], wd[2][4];
    #pragma unroll
    for (int ci = 0; ci < 2; ++ci) {
        f32x4 b4 = *(const f32x4*)(be1 + cb + 16 * ci + hi * 4);
        f32x4 w4 = *(const f32x4*)(w1dist + cb + 16 * ci + hi * 4);
        #pragma unroll
        for (int r = 0; r < 4; ++r) { bv[ci][r] = b4[r]; wd[ci][r] = w4[r]; }
    }
    __syncthreads();   // all A-tile reads done before X overlays it

    // ---- bias + dist rank-1 + SiLU, pack X (bf16) into LDS [0,16K)
    #pragma unroll
    for (int ci = 0; ci < 2; ++ci)
        #pragma unroll
        for (int ej = 0; ej < 4; ++ej) {
            const float dv = s_dist[16 * ej + lo];
            float s0 = silu_f(acc[ci][ej][0] + bv[ci][0] + dv * wd[ci][0]);
            float s1 = silu_f(acc[ci][ej][1] + bv[ci][1] + dv * wd[ci][1]);
            float s2 = silu_f(acc[ci][ej][2] + bv[ci][2] + dv * wd[ci][2]);
            float s3 = silu_f(acc[ci][ej][3] + bv[ci][3] + dv * wd[ci][3]);
            u32x2 u; u[0] = cvtpk(s0, s1); u[1] = cvtpk(s2, s3);
            const int e = 16 * ej + lo, c0 = cb + 16 * ci + hi * 4;
            int b = (e * 256 + c0 * 2) ^ ((e & 7) << 4);
            *(u32x2*)(sbytes + b) = u;
        }
    __syncthreads();

    // ---- GEMM2: K = 128 (4 chunks, weights in regs)
    #pragma unroll
    for (int ci = 0; ci < 2; ++ci)
        #pragma unroll
        for (int ej = 0; ej < 4; ++ej) acc[ci][ej] = (f32x4){0.f, 0.f, 0.f, 0.f};
    {
        #pragma unroll
        for (int kk = 0; kk < 4; ++kk) {
            bf16x8 bfr[4];
            #pragma unroll
            for (int ej = 0; ej < 4; ++ej) {
                int b = ((16 * ej + lo) * 256 + kk * 64 + hi * 16) ^ ((lo & 7) << 4);
                bfr[ej] = *(const bf16x8*)(sbytes + b);
            }
            #pragma unroll
            for (int ej = 0; ej < 4; ++ej) {
                acc[0][ej] = __builtin_amdgcn_mfma_f32_16x16x32_bf16(w2a[kk], bfr[ej], acc[0][ej], 0, 0, 0);
                acc[1][ej] = __builtin_amdgcn_mfma_f32_16x16x32_bf16(w2b[kk], bfr[ej], acc[1][ej], 0, 0, 0);
            }
        }
    }
    // preload GEMM3 weights
    bf16x8 w3a[4], w3b[4];
    {
        const unsigned short* p0 = Wtc1 + (size_t)(cb + lo) * D + hi * 8;
        const unsigned short* p1 = Wtc1 + (size_t)(cb + 16 + lo) * D + hi * 8;
        #pragma unroll
        for (int kk = 0; kk < 4; ++kk) { w3a[kk] = *(const bf16x8*)(p0 + kk * 32); w3b[kk] = *(const bf16x8*)(p1 + kk * 32); }
    }
    #pragma unroll
    for (int ci = 0; ci < 2; ++ci) {
        f32x4 b4 = *(const f32x4*)(be2 + cb + 16 * ci + hi * 4);
        #pragma unroll
        for (int r = 0; r < 4; ++r) bv[ci][r] = b4[r];
    }

    // ---- m_ij = SiLU(...): write bf16 to LDS [16K,32K)
    #pragma unroll
    for (int ci = 0; ci < 2; ++ci)
        #pragma unroll
        for (int ej = 0; ej < 4; ++ej) {
            const int e = 16 * ej + lo, c0 = cb + 16 * ci + hi * 4;
            float s0 = silu_f(acc[ci][ej][0] + bv[ci][0]);
            float s1 = silu_f(acc[ci][ej][1] + bv[ci][1]);
            float s2 = silu_f(acc[ci][ej][2] + bv[ci][2]);
            float s3 = silu_f(acc[ci][ej][3] + bv[ci][3]);
            u32x2 u; u[0] = cvtpk(s0, s1); u[1] = cvtpk(s2, s3);
            int b = 16384 + ((e * 256 + c0 * 2) ^ ((e & 7) << 4));
            *(u32x2*)(sbytes + b) = u;
        }
    __syncthreads();

    // ---- GEMM3 (coord MLP layer 1): K = 128, reads m_ij LDS (weights in regs)
    #pragma unroll
    for (int ci = 0; ci < 2; ++ci)
        #pragma unroll
        for (int ej = 0; ej < 4; ++ej) acc[ci][ej] = (f32x4){0.f, 0.f, 0.f, 0.f};
    {
        #pragma unroll
        for (int kk = 0; kk < 4; ++kk) {
            bf16x8 bfr[4];
            #pragma unroll
            for (int ej = 0; ej < 4; ++ej) {
                int b = 16384 + (((16 * ej + lo) * 256 + kk * 64 + hi * 16) ^ ((lo & 7) << 4));
                bfr[ej] = *(const bf16x8*)(sbytes + b);
            }
            #pragma unroll
            for (int ej = 0; ej < 4; ++ej) {
                acc[0][ej] = __builtin_amdgcn_mfma_f32_16x16x32_bf16(w3a[kk], bfr[ej], acc[0][ej], 0, 0, 0);
                acc[1][ej] = __builtin_amdgcn_mfma_f32_16x16x32_bf16(w3b[kk], bfr[ej], acc[1][ej], 0, 0, 0);
            }
        }
    }

    // ---- segmented reduction of m_ij (CSR-sorted dst) -> atomics into f32 m_i
    {
        const int c = tid & 127;          // channel
        const int rbase = (tid >> 7) * 32;
        float accr = 0.f;
        int dprev = s_dst[rbase];
        #pragma unroll 8
        for (int i = 0; i < 32; ++i) {
            const int r = rbase + i;
            const int d = s_dst[r];
            if (d != dprev) {
                unsafeAtomicAdd(m_i + (size_t)dprev * D + c, accr);
                accr = 0.f; dprev = d;
            }
            int b = 16384 + ((r * 256 + c * 2) ^ ((r & 7) << 4));
            accr += bf2f(*(const unsigned short*)(sbytes + b));
        }
        unsafeAtomicAdd(m_i + (size_t)dprev * D + c, accr);
    }

    // ---- per-lane partial dot with Wc2, reduce over hi-groups, then over waves via LDS
    {
        float wcv[2][4], bcv[2][4];
        #pragma unroll
        for (int ci = 0; ci < 2; ++ci) {
            f32x4 w4 = *(const f32x4*)(wc2 + cb + 16 * ci + hi * 4);
            f32x4 b4 = *(const f32x4*)(bc1 + cb + 16 * ci + hi * 4);
            #pragma unroll
            for (int r = 0; r < 4; ++r) { wcv[ci][r] = w4[r]; bcv[ci][r] = b4[r]; }
        }
        float p[4] = {0.f, 0.f, 0.f, 0.f};
        #pragma unroll
        for (int ci = 0; ci < 2; ++ci)
            #pragma unroll
            for (int ej = 0; ej < 4; ++ej)
                #pragma unroll
                for (int r = 0; r < 4; ++r)
                    p[ej] += silu_f(acc[ci][ej][r] + bcv[ci][r]) * wcv[ci][r];
        #pragma unroll
        for (int ej = 0; ej < 4; ++ej) {
            p[ej] += __shfl_xor(p[ej], 16, 64);
            p[ej] += __shfl_xor(p[ej], 32, 64);
        }
        if (hi == 0) {
            #pragma unroll
            for (int ej = 0; ej < 4; ++ej) cwp[w * MT + 16 * ej + lo] = p[ej];
        }
    }
    __syncthreads();
    if (tid < MT) {
        const float cw = cwp[tid] + cwp[MT + tid] + cwp[2 * MT + tid] + cwp[3 * MT + tid];
        const int ge = s_ge[tid];
        const int s = s_src[tid];
        const float* dc = diff_cart + (size_t)ge * 3;
        unsafeAtomicAdd(coord_out + (size_t)s * 3 + 0, dc[0] * cw);
        unsafeAtomicAdd(coord_out + (size_t)s * 3 + 1, dc[1] * cw);
        unsafeAtomicAdd(coord_out + (size_t)s * 3 + 2, dc[2] * cw);
    }
}

// ---------------------------------------------------------------- node kernel: h + MLP([h | m_i | t_emb])
__global__ __launch_bounds__(256, 3) void node_kernel(
    const float* __restrict__ h, const float* __restrict__ m_i,
    const float* __restrict__ tembn,
    const unsigned short* __restrict__ Wtn1, const float* __restrict__ bn1,
    const unsigned short* __restrict__ Wtn2, const float* __restrict__ bn2,
    float* __restrict__ out)
{
    __shared__ __align__(16) unsigned short smem[MT * KN];  // 48KB; X overlays [0,16K)
    char* sbytes = (char*)smem;
    const int tid = threadIdx.x, blk = blockIdx.x;
    const int w = tid >> 6, l = tid & 63, lo = l & 15, hi = l >> 4;
    const int cb = w * 32;

    // ---- build A tile: issue all loads first, then cvt+write
    {
        const int r = tid >> 2, q = tid & 3;
        const int n = blk * MT + r;
        const bool valid = (n < N_NODES);
        const float* hp = h + (size_t)n * D;
        const float* mp = m_i + (size_t)n * D;
        const float* tp = tembn + (size_t)n * T;
        f32x4 va[12][2];
        #pragma unroll
        for (int i = 0; i < 12; ++i) {
            const int col = (q * 12 + i) * 8;
            if (valid) {
                const float* p = (col < 128) ? (hp + col) : (col < 256) ? (mp + col - 128) : (tp + col - 256);
                va[i][0] = *(const f32x4*)p;
                va[i][1] = *(const f32x4*)(p + 4);
            } else {
                va[i][0] = (f32x4){0.f,0.f,0.f,0.f};
                va[i][1] = (f32x4){0.f,0.f,0.f,0.f};
            }
        }
        #pragma unroll
        for (int i = 0; i < 12; ++i) {
            const int col = (q * 12 + i) * 8;
            u32x4 u;
            u[0] = cvtpk(va[i][0][0], va[i][0][1]); u[1] = cvtpk(va[i][0][2], va[i][0][3]);
            u[2] = cvtpk(va[i][1][0], va[i][1][1]); u[3] = cvtpk(va[i][1][2], va[i][1][3]);
            int b = (r * (KN * 2) + col * 2) ^ ((r & 7) << 4);
            *(u32x4*)(sbytes + b) = u;
        }
    }
    __syncthreads();

    // ---- GEMM1: K = 384 (12 chunks)
    f32x4 acc[2][4];
    #pragma unroll
    for (int ci = 0; ci < 2; ++ci)
        #pragma unroll
        for (int ej = 0; ej < 4; ++ej) acc[ci][ej] = (f32x4){0.f, 0.f, 0.f, 0.f};
    {
        const unsigned short* w0 = Wtn1 + (size_t)(cb + lo) * KN + hi * 8;
        const unsigned short* w1 = Wtn1 + (size_t)(cb + 16 + lo) * KN + hi * 8;
        #pragma unroll
        for (int kk = 0; kk < 12; ++kk) {
            bf16x8 a0 = *(const bf16x8*)(w0 + kk * 32);
            bf16x8 a1 = *(const bf16x8*)(w1 + kk * 32);
            bf16x8 bfr[4];
            #pragma unroll
            for (int ej = 0; ej < 4; ++ej) {
                int b = ((16 * ej + lo) * (KN * 2) + kk * 64 + hi * 16) ^ ((lo & 7) << 4);
                bfr[ej] = *(const bf16x8*)(sbytes + b);
            }
            #pragma unroll
            for (int ej = 0; ej < 4; ++ej) {
                acc[0][ej] = __builtin_amdgcn_mfma_f32_16x16x32_bf16(a0, bfr[ej], acc[0][ej], 0, 0, 0);
                acc[1][ej] = __builtin_amdgcn_mfma_f32_16x16x32_bf16(a1, bfr[ej], acc[1][ej], 0, 0, 0);
            }
        }
    }
    // preload GEMM2 weights
    bf16x8 w2a[4], w2b[4];
    {
        const unsigned short* p0 = Wtn2 + (size_t)(cb + lo) * D + hi * 8;
        const unsigned short* p1 = Wtn2 + (size_t)(cb + 16 + lo) * D + hi * 8;
        #pragma unroll
        for (int kk = 0; kk < 4; ++kk) { w2a[kk] = *(const bf16x8*)(p0 + kk * 32); w2b[kk] = *(const bf16x8*)(p1 + kk * 32); }
    }
    float bv[2][4];
    #pragma unroll
    for (int ci = 0; ci < 2; ++ci) {
        f32x4 b4 = *(const f32x4*)(bn1 + cb + 16 * ci + hi * 4);
        #pragma unroll
        for (int r = 0; r < 4; ++r) bv[ci][r] = b4[r];
    }
    __syncthreads();

    // ---- bias+SiLU -> X
    #pragma unroll
    for (int ci = 0; ci < 2; ++ci)
        #pragma unroll
        for (int ej = 0; ej < 4; ++ej) {
            float s0 = silu_f(acc[ci][ej][0] + bv[ci][0]);
            float s1 = silu_f(acc[ci][ej][1] + bv[ci][1]);
            float s2 = silu_f(acc[ci][ej][2] + bv[ci][2]);
            float s3 = silu_f(acc[ci][ej][3] + bv[ci][3]);
            u32x2 u; u[0] = cvtpk(s0, s1); u[1] = cvtpk(s2, s3);
            const int e = 16 * ej + lo, c0 = cb + 16 * ci + hi * 4;
            int b = (e * 256 + c0 * 2) ^ ((e & 7) << 4);
            *(u32x2*)(sbytes + b) = u;
        }
    __syncthreads();

    // ---- GEMM2: K = 128 (weights in regs)
    #pragma unroll
    for (int ci = 0; ci < 2; ++ci)
        #pragma unroll
        for (int ej = 0; ej < 4; ++ej) acc[ci][ej] = (f32x4){0.f, 0.f, 0.f, 0.f};
    {
        #pragma unroll
        for (int kk = 0; kk < 4; ++kk) {
            bf16x8 bfr[4];
            #pragma unroll
            for (int ej = 0; ej < 4; ++ej) {
                int b = ((16 * ej + lo) * 256 + kk * 64 + hi * 16) ^ ((lo & 7) << 4);
                bfr[ej] = *(const bf16x8*)(sbytes + b);
            }
            #pragma unroll
            for (int ej = 0; ej < 4; ++ej) {
                acc[0][ej] = __builtin_amdgcn_mfma_f32_16x16x32_bf16(w2a[kk], bfr[ej], acc[0][ej], 0, 0, 0);
                acc[1][ej] = __builtin_amdgcn_mfma_f32_16x16x32_bf16(w2b[kk], bfr[ej], acc[1][ej], 0, 0, 0);
            }
        }
    }
    #pragma unroll
    for (int ci = 0; ci < 2; ++ci) {
        f32x4 b4 = *(const f32x4*)(bn2 + cb + 16 * ci + hi * 4);
        #pragma unroll
        for (int r = 0; r < 4; ++r) bv[ci][r] = b4[r];
    }

    // ---- epilogue: + bias + residual, coalesced f32x4 stores
    #pragma unroll
    for (int ej = 0; ej < 4; ++ej) {
        const int e = 16 * ej + lo;
        const int n2 = blk * MT + e;
        if (n2 < N_NODES) {
            #pragma unroll
            for (int ci = 0; ci < 2; ++ci) {
                const int c0 = cb + 16 * ci + hi * 4;
                f32x4 hres = *(const f32x4*)(h + (size_t)n2 * D + c0);
                f32x4 o;
                #pragma unroll
                for (int r = 0; r < 4; ++r) o[r] = acc[ci][ej][r] + bv[ci][r] + hres[r];
                *(f32x4*)(out + (size_t)n2 * D + c0) = o;
            }
        }
    }
}

// ---------------------------------------------------------------- launcher
extern "C" void kernel_launch(void* const* d_in, const int* in_sizes, int n_in,
                              void* d_out, int out_size, void* d_ws, size_t ws_size,
                              hipStream_t stream) {
    const float* h    = (const float*)d_in[0];
    const float* diff = (const float*)d_in[1];
    const float* dsq  = (const float*)d_in[2];
    const int*   esrc = (const int*)d_in[3];
    const int*   edst = (const int*)d_in[4];
    const float* tEe  = (const float*)d_in[5];
    const float* tEn  = (const float*)d_in[6];
    const float* We1  = (const float*)d_in[7];
    const float* be1  = (const float*)d_in[8];
    const float* We2  = (const float*)d_in[9];
    const float* be2  = (const float*)d_in[10];
    const float* Wc1  = (const float*)d_in[11];
    const float* bc1  = (const float*)d_in[12];
    const float* Wc2  = (const float*)d_in[13];
    const float* Wn1  = (const float*)d_in[14];
    const float* bn1  = (const float*)d_in[15];
    const float* Wn2  = (const float*)d_in[16];
    const float* bn2  = (const float*)d_in[17];

    float* out = (float*)d_out;
    float* coord_out = out + (size_t)N_NODES * D;

    char* ws = (char*)d_ws;
    size_t off_b = 0;
    float* m_i = (float*)(ws + off_b); off_b += (size_t)N_NODES * D * 4;   // 25.6 MB
    unsigned short* Wt1  = (unsigned short*)(ws + off_b); off_b += (size_t)D * KE * 2;
    unsigned short* Wt2  = (unsigned short*)(ws + off_b); off_b += (size_t)D * D * 2;
    unsigned short* Wtc1 = (unsigned short*)(ws + off_b); off_b += (size_t)D * D * 2;
    unsigned short* Wtn1 = (unsigned short*)(ws + off_b); off_b += (size_t)D * KN * 2;
    unsigned short* Wtn2 = (unsigned short*)(ws + off_b); off_b += (size_t)D * D * 2;
    float* w1dist = (float*)(ws + off_b); off_b += (size_t)D * 4;
    int* cnt  = (int*)(ws + off_b); off_b += (size_t)N_NODES * 4;
    int* csoff= (int*)(ws + off_b); off_b += (size_t)(N_NODES + 1) * 4;
    int* cur  = (int*)(ws + off_b); off_b += (size_t)N_NODES * 4;
    int* eidx = (int*)(ws + off_b); off_b += (size_t)N_EDGES * 4;

    hipMemsetAsync(cnt, 0, (size_t)N_NODES * 4, stream);
    hipMemsetAsync(m_i, 0, (size_t)N_NODES * D * 4, stream);
    hipMemsetAsync(coord_out, 0, (size_t)N_NODES * 3 * sizeof(float), stream);

    prep_weights<<<dim3(D), dim3(256), 0, stream>>>(We1, We2, Wc1, Wn1, Wn2,
                                                    Wt1, Wt2, Wtc1, Wtn1, Wtn2, w1dist);
    hist_kernel<<<dim3((N_EDGES + 255) / 256), dim3(256), 0, stream>>>(edst, cnt);
    scan_kernel<<<dim3(1), dim3(1024), 0, stream>>>(cnt, csoff, cur);
    fill_kernel<<<dim3((N_EDGES + 255) / 256), dim3(256), 0, stream>>>(edst, cur, eidx);
    edge_kernel<<<dim3(N_EDGES / MT), dim3(256), 0, stream>>>(
        h, diff, dsq, esrc, edst, tEe, eidx, Wt1, be1, Wt2, be2, Wtc1, bc1, Wc2, w1dist, m_i, coord_out);
    node_kernel<<<dim3((N_NODES + MT - 1) / MT), dim3(256), 0, stream>>>(
        h, m_i, tEn, Wtn1, bn1, Wtn2, bn2, out);
}